// Round 7
// baseline (169.496 us; speedup 1.0000x reference)
//
#include <hip/hip_runtime.h>
#include <hip/hip_bf16.h>

// MultiHead attention, MI355X/gfx950. fp32 in/out, bf16 MFMA internals.
// B=2, T=2048, C=1024, H=16, D=64.
// Round 14: attn = R13 quadrant-split kernel with the k-loop UNROLLED x2 so
// the LDS buffer index is a compile-time literal: all 8 fragment ds_reads
// collapse to base-VGPR + offset:imm (zero per-tile address VALU), staging
// pointers become pure induction (+=). R12 counters showed VALU-busy ~17us
// at 16 waves/CU -- mostly per-tile address recompute, not exp/cvt. Compute,
// kperm, swizzle, combine epilogue byte-identical to verified R13.
//
// ws layout (bf16 elems):
//   xb  [4096][1024]            @ 0          (x as bf16)
//   wt  [3][16][64][1024]       @ 4194304    (= fused Bt [3072][1024])
//   wot [1024][1024]            @ 7340032    (Wo transposed, bf16)
//   qkv Q,K:[h][b*2048+t][d] Vt:[h][b][d][t] @ 8388608  (Q pre-scaled log2e/32)
//   att [4096][1024]            @ 20971520
// total 25165824 elems = 48 MB

typedef __hip_bfloat16 bf16;
typedef __bf16 v8bf __attribute__((ext_vector_type(8)));
typedef float  v4f  __attribute__((ext_vector_type(4)));
typedef unsigned long long u64;
typedef unsigned int u32;

#define MFMA16(a, b, c) __builtin_amdgcn_mfma_f32_16x16x32_bf16((a), (b), (c), 0, 0, 0)

__device__ __forceinline__ bf16 f2b(float x) { return __float2bfloat16(x); }
__device__ __forceinline__ __bf16 f2braw(float x) {
  bf16 t = __float2bfloat16(x);
  return *reinterpret_cast<__bf16*>(&t);
}
__device__ __forceinline__ unsigned short f2bu(float x) {
  bf16 t = __float2bfloat16(x);
  return *reinterpret_cast<unsigned short*>(&t);
}

// async global->LDS, 16B per lane; LDS dest = wave-uniform base + lane*16.
__device__ __forceinline__ void load16_lds(const bf16* gptr, const bf16* lptr) {
  __builtin_amdgcn_global_load_lds(
      (const __attribute__((address_space(1))) u32*)gptr,
      (__attribute__((address_space(3))) u32*)lptr, 16, 0, 0);
}

// ---------------------------------------------------------------------------
// Fused prep: [0,2048) cvt_x | [2048,5120) Wq/Wk/Wv transpose | [5120,6144) Wo.
// ---------------------------------------------------------------------------
__global__ __launch_bounds__(256) void prep_kernel(
    const float* __restrict__ x,
    const float* __restrict__ Wq, const float* __restrict__ Wk,
    const float* __restrict__ Wv, const float* __restrict__ Wo,
    bf16* __restrict__ xb, bf16* __restrict__ wt, bf16* __restrict__ wot)
{
  __shared__ float Lt[32][33];
  const int bid = blockIdx.x, tid = threadIdx.x;

  if (bid < 2048) {                        // x fp32 -> bf16
    size_t i = ((size_t)bid * 256 + tid) * 8;
    float4 f0 = *(const float4*)(x + i);
    float4 f1 = *(const float4*)(x + i + 4);
    v8bf v;
    v[0] = f2braw(f0.x); v[1] = f2braw(f0.y); v[2] = f2braw(f0.z); v[3] = f2braw(f0.w);
    v[4] = f2braw(f1.x); v[5] = f2braw(f1.y); v[6] = f2braw(f1.z); v[7] = f2braw(f1.w);
    *(v8bf*)(xb + i) = v;
    return;
  }
  const int tx = tid & 31, ty = tid >> 5;
  if (bid < 5120) {                        // Wq/Wk/Wv [h][1024][64] -> wt [z][64][1024]
    const int idx = bid - 2048;
    const int z = idx >> 6, rem = idx & 63;
    const int p = z >> 4, h = z & 15;
    const float* ib = ((p == 0) ? Wq : (p == 1) ? Wk : Wv) + (size_t)h * 65536;
    bf16* ob = wt + (size_t)z * 65536;
    const int j0 = (rem & 1) * 32, i0 = (rem >> 1) * 32;
    #pragma unroll
    for (int r = 0; r < 4; ++r)
      Lt[ty + 8 * r][tx] = ib[(size_t)(i0 + ty + 8 * r) * 64 + j0 + tx];
    __syncthreads();
    #pragma unroll
    for (int r = 0; r < 4; ++r)
      ob[(size_t)(j0 + ty + 8 * r) * 1024 + i0 + tx] = f2b(Lt[tx][ty + 8 * r]);
  } else {                                 // Wo [1024][1024] -> wot transposed
    const int idx = bid - 5120;
    const int j0 = (idx & 31) * 32, i0 = (idx >> 5) * 32;
    #pragma unroll
    for (int r = 0; r < 4; ++r)
      Lt[ty + 8 * r][tx] = Wo[(size_t)(i0 + ty + 8 * r) * 1024 + j0 + tx];
    __syncthreads();
    #pragma unroll
    for (int r = 0; r < 4; ++r)
      wot[(size_t)(j0 + ty + 8 * r) * 1024 + i0 + tx] = f2b(Lt[tx][ty + 8 * r]);
  }
}

// ---------------------------------------------------------------------------
// Kernel 1: fused QKV GEMM, M=4096 x N=3072, K=1024. 128x128 tile, BK=32,
// double-buffered LDS, ONE barrier per k-step. grid (32 mt, 24 nt).
// Epilogue scatters Q,K ([h][m][d], Q*log2e/32) and V transposed
// ([h][b][d][t]).
// ---------------------------------------------------------------------------
__global__ __launch_bounds__(256) void qkv_gemm_kernel(
    const bf16* __restrict__ xb, const bf16* __restrict__ wt,
    bf16* __restrict__ qkv)
{
  __shared__ __align__(16) bf16 Ash[2][128][32];
  __shared__ __align__(16) bf16 Bsh[2][128][32];

  const int mt = blockIdx.x, nt = blockIdx.y;
  const int tid = threadIdx.x, w = tid >> 6, lane = tid & 63;
  const int ln = lane & 15, quad = lane >> 4;
  const int wm = w >> 1, wn = w & 1;
  const int m0 = mt * 128, n0 = nt * 128;

  const v4f vzero = {0.f, 0.f, 0.f, 0.f};
  v4f acc[4][4];
  #pragma unroll
  for (int mf = 0; mf < 4; ++mf)
    #pragma unroll
    for (int nf = 0; nf < 4; ++nf) acc[mf][nf] = vzero;

  const int srow = lane >> 2, sseg = (lane & 3) * 8;
  const bf16* ga = xb + (size_t)(m0 + 32 * w + srow) * 1024 + sseg;
  const bf16* gb = wt + (size_t)(n0 + 32 * w + srow) * 1024 + sseg;

  // prologue: stage k-step 0 into buf 0
  {
    load16_lds(ga,             &Ash[0][32 * w][0]);
    load16_lds(ga + 16 * 1024, &Ash[0][32 * w + 16][0]);
    load16_lds(gb,             &Bsh[0][32 * w][0]);
    load16_lds(gb + 16 * 1024, &Bsh[0][32 * w + 16][0]);
  }

  for (int kt = 0; kt < 32; ++kt) {
    const int buf = kt & 1;
    __syncthreads();                       // publishes buf (drains loads)

    v8bf af[4], bfv[4];
    #pragma unroll
    for (int mf = 0; mf < 4; ++mf)
      af[mf] = *(const v8bf*)&Ash[buf][wm * 64 + mf * 16 + ln][quad * 8];
    #pragma unroll
    for (int nf = 0; nf < 4; ++nf)
      bfv[nf] = *(const v8bf*)&Bsh[buf][wn * 64 + nf * 16 + ln][quad * 8];

    if (kt < 31) {                         // stage kt+1 into other buffer
      const int k0 = (kt + 1) * 32, nb = buf ^ 1;
      load16_lds(ga + k0,             &Ash[nb][32 * w][0]);
      load16_lds(ga + 16 * 1024 + k0, &Ash[nb][32 * w + 16][0]);
      load16_lds(gb + k0,             &Bsh[nb][32 * w][0]);
      load16_lds(gb + 16 * 1024 + k0, &Bsh[nb][32 * w + 16][0]);
    }

    #pragma unroll
    for (int mf = 0; mf < 4; ++mf)
      #pragma unroll
      for (int nf = 0; nf < 4; ++nf)
        acc[mf][nf] = MFMA16(af[mf], bfv[nf], acc[mf][nf]);
  }

  const int jcol0 = n0 + wn * 64;
  const int p = jcol0 >> 10;
  const int h = (jcol0 >> 6) & 15;
  // Q pre-scale: (1/sqrt(1024)) * log2(e), so attn can use exp2 directly.
  const float scale = (p == 0) ? 0.0450841149f : 1.0f;

  if (p < 2) {                               // Q, K: [h][m][d]
    bf16* base = qkv + (size_t)p * 4194304 + (size_t)h * 262144;
    #pragma unroll
    for (int mf = 0; mf < 4; ++mf)
      #pragma unroll
      for (int nf = 0; nf < 4; ++nf) {
        int d = nf * 16 + ln;
        #pragma unroll
        for (int r = 0; r < 4; ++r) {
          int m = m0 + wm * 64 + mf * 16 + quad * 4 + r;
          base[(size_t)m * 64 + d] = f2b(acc[mf][nf][r] * scale);
        }
      }
  } else {                                   // V transposed: [h][b][d][t]
    bf16* vb = qkv + (size_t)2 * 4194304 + (size_t)h * 262144;
    #pragma unroll
    for (int mf = 0; mf < 4; ++mf) {
      int mrow = m0 + wm * 64 + mf * 16 + quad * 4;
      int bi = mrow >> 11, t0 = mrow & 2047;
      #pragma unroll
      for (int nf = 0; nf < 4; ++nf) {
        int d = nf * 16 + ln;
        u64 pk = (u64)f2bu(acc[mf][nf][0]) |
                 ((u64)f2bu(acc[mf][nf][1]) << 16) |
                 ((u64)f2bu(acc[mf][nf][2]) << 32) |
                 ((u64)f2bu(acc[mf][nf][3]) << 48);
        *(u64*)(vb + (size_t)bi * 131072 + (size_t)d * 2048 + t0) = pk;
      }
    }
  }
}

// ---------------------------------------------------------------------------
// Kernel 2: causal flash attention, swapped-QK^T in-register softmax,
// QUADRANT-SPLIT waves (R13), k-loop unrolled x2 for compile-time buffers.
// Block = 4 waves, 64 q-rows, trips = mt+1 k-tiles. Wave w = (qh=w&1,
// kh=w>>1) computes the 32q x 32kv quadrant (8KB LDS reads/wave-tile).
// kv-half partials combined once per block via LDS scratch unioned over the
// dead K/V buffers. Staging kperm + slot swizzle identical to R12/R13.
// grid 1024 x 256thr, 4 blocks/CU; mt via 4-phase balanced table.
// ---------------------------------------------------------------------------
__global__ __launch_bounds__(256, 4) void attn_kernel(
    const bf16* __restrict__ qkv, bf16* __restrict__ att)
{
  union ShU {
    struct { bf16 K[2][64][64]; bf16 V[2][64][64]; } t;   // 32 KB tiles
    struct { float O[2][64][36]; float L[2][36]; } c;     // 18.7 KB combine
  };
  __shared__ __align__(16) ShU sh;

  const int fid = blockIdx.x;              // 0..1023
  const int j = fid >> 5;                  // 0..31
  const int jr = j & 7, jq = j >> 3;
  // 4-phase balanced mt table: {31-r, 8+r, 23-r, r}
  const int mt = (jq == 0) ? (31 - jr) : (jq == 1) ? (8 + jr)
               : (jq == 2) ? (23 - jr) : jr;
  const int grp = fid & 31;                // fid%8 == grp%8 -> same-grp same XCD
  const int b = grp >> 4, h = grp & 15;

  const int tid = threadIdx.x, w = tid >> 6, lane = tid & 63;
  const int ln = lane & 15, quad = lane >> 4;
  const int qh = w & 1, kh = w >> 1;       // quadrant ownership

  const bf16* qbase  = qkv + (size_t)h * 262144 + (size_t)b * 131072;
  const bf16* kbase  = qbase + 4194304;
  const bf16* vtbase = qbase + 8388608;    // [d][t], d-stride 2048

  // ---- staging lane constants (wave w stages LDS rows w*16..w*16+15) ----
  const int l8 = lane & 7, r8 = lane >> 3;
  const int slot = l8 ^ r8;                // swizzle: LDS[row][s] = G[row][s^(row&7)]
  const int p0 = w * 16 + r8, p1 = p0 + 8;
  // kperm(p): LDS row p holds K row (p&32) | ((p&12)<<1) | ((p&16)>>2) | (p&3)
  const int kp0 = (p0 & 32) | ((p0 & 12) << 1) | ((p0 & 16) >> 2) | (p0 & 3);
  const int kp1 = (p1 & 32) | ((p1 & 12) << 1) | ((p1 & 16) >> 2) | (p1 & 3);
  const bf16* gkp0 = kbase + kp0 * 64 + slot * 8;   // advanced by +4096/tile
  const bf16* gkp1 = kbase + kp1 * 64 + slot * 8;
  const bf16* gvp0 = vtbase + p0 * 2048 + slot * 8; // advanced by +64/tile
  const bf16* gvp1 = gvp0 + 8 * 2048;

  // ---- fragment-read lane constants (element offsets into [64][64]) ----
  const int sw = ln & 7;
  const int cc0 = ((quad    ) ^ sw) * 8;   // granule for d/kv half 0
  const int cc1 = ((quad + 4) ^ sw) * 8;   // granule for d/kv half 1
  const int cck = kh ? cc1 : cc0;          // V col granule for this kv-half
  const int krow0 = (kh * 32 + ln) * 64;   // K row offset, nfl=0 (elems)
  const int ka0 = krow0 + cc0, ka1 = krow0 + cc1;   // loop-invariant bases
  const int voff = ln * 64 + cck;

  v8bf vone;
  {
    unsigned short u = 0x3F80;             // 1.0 bf16
    __bf16 e = *reinterpret_cast<__bf16*>(&u);
    #pragma unroll
    for (int jj = 0; jj < 8; ++jj) vone[jj] = e;
  }
  const v4f vzero = {0.f, 0.f, 0.f, 0.f};
  const float NEG = -30000.0f;

  #define STAGE2(BUF) {                                          \
    load16_lds(gkp0, &sh.t.K[BUF][w * 16][0]);                   \
    load16_lds(gkp1, &sh.t.K[BUF][w * 16 + 8][0]);               \
    load16_lds(gvp0, &sh.t.V[BUF][w * 16][0]);                   \
    load16_lds(gvp1, &sh.t.V[BUF][w * 16 + 8][0]);               \
    gkp0 += 4096; gkp1 += 4096; gvp0 += 64; gvp1 += 64; }

  const int row0 = mt * 64;
  const int qrow = row0 + qh * 32;         // wave's q rows: qrow..qrow+31

  // Q fragments (B-operand): Q[qrow+mc*16+ln][ks*32 + quad*8 + j]
  v8bf aq[2][2];
  #pragma unroll
  for (int mc = 0; mc < 2; ++mc)
    #pragma unroll
    for (int ks = 0; ks < 2; ++ks)
      aq[mc][ks] = *(const v8bf*)(qbase +
          (size_t)(qrow + mc * 16 + ln) * 64 + ks * 32 + quad * 8);

  v4f o[2][4], lacc[2];
  #pragma unroll
  for (int mc = 0; mc < 2; ++mc) {
    lacc[mc] = vzero;
    #pragma unroll
    for (int dt = 0; dt < 4; ++dt) o[mc][dt] = vzero;
  }

  const int kb_end = mt;
  int kb = 0;
  STAGE2(0)                                // stage kb=0; ptrs now at kb=1

  // TILE(BUF): BUF is a compile-time literal -> ds_read addrs fold to
  // base VGPR + offset:imm; zero per-tile address VALU.
  #define TILE(BUF)                                                        \
  {                                                                        \
    __syncthreads();                       /* publishes BUF */             \
    const bf16* krB = &sh.t.K[BUF][0][0];                                  \
    const bf16* vrB = &sh.t.V[BUF][0][0];                                  \
    v8bf kf[2][2], vf[4];                                                  \
    kf[0][0] = *(const v8bf*)(krB + ka0);                                  \
    kf[1][0] = *(const v8bf*)(krB + ka1);                                  \
    kf[0][1] = *(const v8bf*)(krB + ka0 + 1024);                           \
    kf[1][1] = *(const v8bf*)(krB + ka1 + 1024);                           \
    vf[0] = *(const v8bf*)(vrB + voff);                                    \
    vf[1] = *(const v8bf*)(vrB + voff + 1024);                             \
    vf[2] = *(const v8bf*)(vrB + voff + 2048);                             \
    vf[3] = *(const v8bf*)(vrB + voff + 3072);                             \
    if (kb < kb_end) STAGE2(BUF ^ 1)                                       \
    _Pragma("unroll")                                                      \
    for (int mc = 0; mc < 2; ++mc) {                                       \
      __builtin_amdgcn_s_setprio(1);                                       \
      v4f s[2];                                                            \
      s[0] = vzero; s[1] = vzero;                                          \
      _Pragma("unroll")                                                    \
      for (int ks = 0; ks < 2; ++ks) {                                     \
        s[0] = MFMA16(kf[ks][0], aq[mc][ks], s[0]);                        \
        s[1] = MFMA16(kf[ks][1], aq[mc][ks], s[1]);                        \
      }                                                                    \
      __builtin_amdgcn_s_setprio(0);                                       \
      const int qg = qrow + mc * 16 + ln;                                  \
      if (kb == kb_end) {                  /* causal mask (diagonal) */    \
        _Pragma("unroll")                                                  \
        for (int nfl = 0; nfl < 2; ++nfl) {                                \
          const int kc = kb * 64 + kh * 32 + quad * 8 + nfl * 4;           \
          _Pragma("unroll")                                                \
          for (int r = 0; r < 4; ++r)                                      \
            if (kc + r > qg) s[nfl][r] = NEG;                              \
        }                                                                  \
      }                                                                    \
      float ex[2][4];                                                      \
      _Pragma("unroll")                                                    \
      for (int nfl = 0; nfl < 2; ++nfl)                                    \
        _Pragma("unroll")                                                  \
        for (int r = 0; r < 4; ++r)                                        \
          ex[nfl][r] = exp2f(s[nfl][r]);                                   \
      union { u32 uw[4]; v8bf v; } pu;                                     \
      _Pragma("unroll")                                                    \
      for (int nfl = 0; nfl < 2; ++nfl)                                    \
        _Pragma("unroll")                                                  \
        for (int wi = 0; wi < 2; ++wi)                                     \
          asm("v_cvt_pk_bf16_f32 %0, %1, %2"                               \
              : "=v"(pu.uw[nfl * 2 + wi])                                  \
              : "v"(ex[nfl][2 * wi]), "v"(ex[nfl][2 * wi + 1]));           \
      __builtin_amdgcn_s_setprio(1);                                       \
      lacc[mc] = MFMA16(pu.v, vone, lacc[mc]);                             \
      _Pragma("unroll")                                                    \
      for (int dt = 0; dt < 4; ++dt)                                       \
        o[mc][dt] = MFMA16(pu.v, vf[dt], o[mc][dt]);                       \
      __builtin_amdgcn_s_setprio(0);                                       \
    }                                                                      \
  }

  while (true) {
    TILE(0)
    if (kb >= kb_end) break;
    ++kb;
    TILE(1)
    if (kb >= kb_end) break;
    ++kb;
  }
  #undef TILE
  #undef STAGE2

  // ---- combine kv-half partials (kh=1 -> LDS, kh=0 adds) & epilogue ----
  __syncthreads();                         // all tile reads done; t is dead
  if (kh == 1) {
    #pragma unroll
    for (int mc = 0; mc < 2; ++mc) {
      #pragma unroll
      for (int dt = 0; dt < 4; ++dt)
        *(v4f*)&sh.c.O[qh][dt * 16 + ln][mc * 16 + quad * 4] = o[mc][dt];
      if (ln == 0)
        *(v4f*)&sh.c.L[qh][mc * 16 + quad * 4] = lacc[mc];
    }
  }
  __syncthreads();
  if (kh == 0) {
    #pragma unroll
    for (int mc = 0; mc < 2; ++mc) {
      v4f pl = *(const v4f*)&sh.c.L[qh][mc * 16 + quad * 4];
      v4f inv;
      #pragma unroll
      for (int r = 0; r < 4; ++r) inv[r] = 1.0f / (lacc[mc][r] + pl[r]);
      #pragma unroll
      for (int dt = 0; dt < 4; ++dt) {
        v4f po = *(const v4f*)&sh.c.O[qh][dt * 16 + ln][mc * 16 + quad * 4];
        #pragma unroll
        for (int r = 0; r < 4; ++r) {
          int m = b * 2048 + qrow + mc * 16 + quad * 4 + r;
          att[(size_t)m * 1024 + h * 64 + dt * 16 + ln] =
              f2b((o[mc][dt][r] + po[r]) * inv[r]);
        }
      }
    }
  }
}

// ---------------------------------------------------------------------------
// Kernel 3: output projection + bias, fp32 out. 128x64 tiles, BK=32,
// double-buffered, ONE barrier per k-step. grid (32 mt, 16 nt).
// ---------------------------------------------------------------------------
__global__ __launch_bounds__(256) void out_gemm_kernel(
    const bf16* __restrict__ att, const bf16* __restrict__ wot,
    const float* __restrict__ bo, float* __restrict__ out)
{
  __shared__ __align__(16) bf16 Ash[2][128][32];
  __shared__ __align__(16) bf16 Bsh[2][64][32];

  const int mt = blockIdx.x, nt = blockIdx.y;
  const int tid = threadIdx.x, w = tid >> 6, lane = tid & 63;
  const int ln = lane & 15, quad = lane >> 4;
  const int wm = w >> 1, wn = w & 1;
  const int m0 = mt * 128, n0 = nt * 64;

  const v4f vzero = {0.f, 0.f, 0.f, 0.f};
  v4f acc[4][2];
  #pragma unroll
  for (int mf = 0; mf < 4; ++mf)
    #pragma unroll
    for (int nf = 0; nf < 2; ++nf) acc[mf][nf] = vzero;

  const int srow = lane >> 2, sseg = (lane & 3) * 8;
  const bf16* ga = att + (size_t)(m0 + 32 * w + srow) * 1024 + sseg;
  const bf16* gb = wot + (size_t)(n0 + 16 * w + srow) * 1024 + sseg;

  {
    load16_lds(ga,             &Ash[0][32 * w][0]);
    load16_lds(ga + 16 * 1024, &Ash[0][32 * w + 16][0]);
    load16_lds(gb,             &Bsh[0][16 * w][0]);
  }

  for (int kt = 0; kt < 32; ++kt) {
    const int buf = kt & 1;
    __syncthreads();

    v8bf af[4], bfv[2];
    #pragma unroll
    for (int mf = 0; mf < 4; ++mf)
      af[mf] = *(const v8bf*)&Ash[buf][wm * 64 + mf * 16 + ln][quad * 8];
    #pragma unroll
    for (int nf = 0; nf < 2; ++nf)
      bfv[nf] = *(const v8bf*)&Bsh[buf][wn * 32 + nf * 16 + ln][quad * 8];

    if (kt < 31) {
      const int k0 = (kt + 1) * 32, nb = buf ^ 1;
      load16_lds(ga + k0,             &Ash[nb][32 * w][0]);
      load16_lds(ga + 16 * 1024 + k0, &Ash[nb][32 * w + 16][0]);
      load16_lds(gb + k0,             &Bsh[nb][16 * w][0]);
    }

    #pragma unroll
    for (int mf = 0; mf < 4; ++mf)
      #pragma unroll
      for (int nf = 0; nf < 2; ++nf)
        acc[mf][nf] = MFMA16(af[mf], bfv[nf], acc[mf][nf]);
  }

  #pragma unroll
  for (int nf = 0; nf < 2; ++nf) {
    int j = n0 + wn * 32 + nf * 16 + ln;
    float bias = bo[j];
    #pragma unroll
    for (int mf = 0; mf < 4; ++mf)
      #pragma unroll
      for (int r = 0; r < 4; ++r) {
        int m = m0 + wm * 64 + mf * 16 + quad * 4 + r;
        out[(size_t)m * 1024 + j] = acc[mf][nf][r] + bias;
      }
  }
}

extern "C" void kernel_launch(void* const* d_in, const int* in_sizes, int n_in,
                              void* d_out, int out_size, void* d_ws, size_t ws_size,
                              hipStream_t stream) {
  const float* x  = (const float*)d_in[0];
  const float* Wq = (const float*)d_in[1];
  const float* Wk = (const float*)d_in[2];
  const float* Wv = (const float*)d_in[3];
  const float* Wo = (const float*)d_in[4];
  const float* bo = (const float*)d_in[5];
  float* out = (float*)d_out;

  bf16* xb  = (bf16*)d_ws;
  bf16* wt  = xb + 4194304;
  bf16* wot = xb + 7340032;
  bf16* qkv = xb + 8388608;
  bf16* att = xb + 20971520;

  prep_kernel<<<6144, 256, 0, stream>>>(x, Wq, Wk, Wv, Wo, xb, wt, wot);
  qkv_gemm_kernel<<<dim3(32, 24), 256, 0, stream>>>(xb, wt, qkv);
  attn_kernel<<<1024, 256, 0, stream>>>(qkv, att);
  out_gemm_kernel<<<dim3(32, 16), 256, 0, stream>>>(att, wot, bo, out);
}

// Round 8
// 169.263 us; speedup vs baseline: 1.0014x; 1.0014x over previous
//
#include <hip/hip_runtime.h>
#include <hip/hip_bf16.h>

// MultiHead attention, MI355X/gfx950. fp32 in/out, bf16 MFMA internals.
// B=2, T=2048, C=1024, H=16, D=64.
// Round 15: T2 slot-XOR swizzle on BOTH GEMMs' LDS tiles. R14 profile
// caught qkv_gemm at 44.4us with 3.15M SQ_LDS_BANK_CONFLICT: [128][32]bf16
// rows are 64B, so fragment ds_read_b128 at [row][quad*8] is an 8-way
// conflict (8 even-ln lanes on one 4-bank group). Fix (rule #21): LDS slot
// s holds global segment s ^ ((row>>1)&3) -- staging keeps linear
// global_load_lds dest and pre-swizzles the GLOBAL source segment
// (sseg = ((lane&3)^((lane>>3)&3))*8, row-half invariant); fragment reads
// use (quad ^ ((ln>>1)&3))*8 (mf/nf-invariant lane constant). Result:
// 2-way aliasing only (free per m136). Same fix in out_gemm. attn = R14
// (quadrant split + unrolled x2, reconstructs to ~20us). prep untouched.
//
// ws layout (bf16 elems):
//   xb  [4096][1024]            @ 0          (x as bf16)
//   wt  [3][16][64][1024]       @ 4194304    (= fused Bt [3072][1024])
//   wot [1024][1024]            @ 7340032    (Wo transposed, bf16)
//   qkv Q,K:[h][b*2048+t][d] Vt:[h][b][d][t] @ 8388608  (Q pre-scaled log2e/32)
//   att [4096][1024]            @ 20971520
// total 25165824 elems = 48 MB

typedef __hip_bfloat16 bf16;
typedef __bf16 v8bf __attribute__((ext_vector_type(8)));
typedef float  v4f  __attribute__((ext_vector_type(4)));
typedef unsigned long long u64;
typedef unsigned int u32;

#define MFMA16(a, b, c) __builtin_amdgcn_mfma_f32_16x16x32_bf16((a), (b), (c), 0, 0, 0)

__device__ __forceinline__ bf16 f2b(float x) { return __float2bfloat16(x); }
__device__ __forceinline__ __bf16 f2braw(float x) {
  bf16 t = __float2bfloat16(x);
  return *reinterpret_cast<__bf16*>(&t);
}
__device__ __forceinline__ unsigned short f2bu(float x) {
  bf16 t = __float2bfloat16(x);
  return *reinterpret_cast<unsigned short*>(&t);
}

// async global->LDS, 16B per lane; LDS dest = wave-uniform base + lane*16.
__device__ __forceinline__ void load16_lds(const bf16* gptr, const bf16* lptr) {
  __builtin_amdgcn_global_load_lds(
      (const __attribute__((address_space(1))) u32*)gptr,
      (__attribute__((address_space(3))) u32*)lptr, 16, 0, 0);
}

// ---------------------------------------------------------------------------
// Fused prep: [0,2048) cvt_x | [2048,5120) Wq/Wk/Wv transpose | [5120,6144) Wo.
// ---------------------------------------------------------------------------
__global__ __launch_bounds__(256) void prep_kernel(
    const float* __restrict__ x,
    const float* __restrict__ Wq, const float* __restrict__ Wk,
    const float* __restrict__ Wv, const float* __restrict__ Wo,
    bf16* __restrict__ xb, bf16* __restrict__ wt, bf16* __restrict__ wot)
{
  __shared__ float Lt[32][33];
  const int bid = blockIdx.x, tid = threadIdx.x;

  if (bid < 2048) {                        // x fp32 -> bf16
    size_t i = ((size_t)bid * 256 + tid) * 8;
    float4 f0 = *(const float4*)(x + i);
    float4 f1 = *(const float4*)(x + i + 4);
    v8bf v;
    v[0] = f2braw(f0.x); v[1] = f2braw(f0.y); v[2] = f2braw(f0.z); v[3] = f2braw(f0.w);
    v[4] = f2braw(f1.x); v[5] = f2braw(f1.y); v[6] = f2braw(f1.z); v[7] = f2braw(f1.w);
    *(v8bf*)(xb + i) = v;
    return;
  }
  const int tx = tid & 31, ty = tid >> 5;
  if (bid < 5120) {                        // Wq/Wk/Wv [h][1024][64] -> wt [z][64][1024]
    const int idx = bid - 2048;
    const int z = idx >> 6, rem = idx & 63;
    const int p = z >> 4, h = z & 15;
    const float* ib = ((p == 0) ? Wq : (p == 1) ? Wk : Wv) + (size_t)h * 65536;
    bf16* ob = wt + (size_t)z * 65536;
    const int j0 = (rem & 1) * 32, i0 = (rem >> 1) * 32;
    #pragma unroll
    for (int r = 0; r < 4; ++r)
      Lt[ty + 8 * r][tx] = ib[(size_t)(i0 + ty + 8 * r) * 64 + j0 + tx];
    __syncthreads();
    #pragma unroll
    for (int r = 0; r < 4; ++r)
      ob[(size_t)(j0 + ty + 8 * r) * 1024 + i0 + tx] = f2b(Lt[tx][ty + 8 * r]);
  } else {                                 // Wo [1024][1024] -> wot transposed
    const int idx = bid - 5120;
    const int j0 = (idx & 31) * 32, i0 = (idx >> 5) * 32;
    #pragma unroll
    for (int r = 0; r < 4; ++r)
      Lt[ty + 8 * r][tx] = Wo[(size_t)(i0 + ty + 8 * r) * 1024 + j0 + tx];
    __syncthreads();
    #pragma unroll
    for (int r = 0; r < 4; ++r)
      wot[(size_t)(j0 + ty + 8 * r) * 1024 + i0 + tx] = f2b(Lt[tx][ty + 8 * r]);
  }
}

// ---------------------------------------------------------------------------
// Kernel 1: fused QKV GEMM, M=4096 x N=3072, K=1024. 128x128 tile, BK=32,
// double-buffered LDS, ONE barrier per k-step. grid (32 mt, 24 nt).
// LDS slot-swizzled: LDS[row][s] = G[row][s ^ ((row>>1)&3)] (16B slots).
// Epilogue scatters Q,K ([h][m][d], Q*log2e/32) and V transposed
// ([h][b][d][t]).
// ---------------------------------------------------------------------------
__global__ __launch_bounds__(256) void qkv_gemm_kernel(
    const bf16* __restrict__ xb, const bf16* __restrict__ wt,
    bf16* __restrict__ qkv)
{
  __shared__ __align__(16) bf16 Ash[2][128][32];
  __shared__ __align__(16) bf16 Bsh[2][128][32];

  const int mt = blockIdx.x, nt = blockIdx.y;
  const int tid = threadIdx.x, w = tid >> 6, lane = tid & 63;
  const int ln = lane & 15, quad = lane >> 4;
  const int wm = w >> 1, wn = w & 1;
  const int m0 = mt * 128, n0 = nt * 128;

  const v4f vzero = {0.f, 0.f, 0.f, 0.f};
  v4f acc[4][4];
  #pragma unroll
  for (int mf = 0; mf < 4; ++mf)
    #pragma unroll
    for (int nf = 0; nf < 4; ++nf) acc[mf][nf] = vzero;

  // staging: linear LDS dest; global source segment pre-swizzled.
  // row = 32w + (lane>>2); f(row) = (row>>1)&3 = (lane>>3)&3 (16-row inv).
  const int srow = lane >> 2;
  const int sseg = ((lane & 3) ^ ((lane >> 3) & 3)) * 8;
  const bf16* ga = xb + (size_t)(m0 + 32 * w + srow) * 1024 + sseg;
  const bf16* gb = wt + (size_t)(n0 + 32 * w + srow) * 1024 + sseg;

  // fragment-read slot: quad ^ f(row), f = (ln>>1)&3 (mf/nf-invariant).
  const int fseg = (quad ^ ((ln >> 1) & 3)) * 8;

  // prologue: stage k-step 0 into buf 0
  {
    load16_lds(ga,             &Ash[0][32 * w][0]);
    load16_lds(ga + 16 * 1024, &Ash[0][32 * w + 16][0]);
    load16_lds(gb,             &Bsh[0][32 * w][0]);
    load16_lds(gb + 16 * 1024, &Bsh[0][32 * w + 16][0]);
  }

  for (int kt = 0; kt < 32; ++kt) {
    const int buf = kt & 1;
    __syncthreads();                       // publishes buf (drains loads)

    v8bf af[4], bfv[4];
    #pragma unroll
    for (int mf = 0; mf < 4; ++mf)
      af[mf] = *(const v8bf*)&Ash[buf][wm * 64 + mf * 16 + ln][fseg];
    #pragma unroll
    for (int nf = 0; nf < 4; ++nf)
      bfv[nf] = *(const v8bf*)&Bsh[buf][wn * 64 + nf * 16 + ln][fseg];

    if (kt < 31) {                         // stage kt+1 into other buffer
      const int k0 = (kt + 1) * 32, nb = buf ^ 1;
      load16_lds(ga + k0,             &Ash[nb][32 * w][0]);
      load16_lds(ga + 16 * 1024 + k0, &Ash[nb][32 * w + 16][0]);
      load16_lds(gb + k0,             &Bsh[nb][32 * w][0]);
      load16_lds(gb + 16 * 1024 + k0, &Bsh[nb][32 * w + 16][0]);
    }

    #pragma unroll
    for (int mf = 0; mf < 4; ++mf)
      #pragma unroll
      for (int nf = 0; nf < 4; ++nf)
        acc[mf][nf] = MFMA16(af[mf], bfv[nf], acc[mf][nf]);
  }

  const int jcol0 = n0 + wn * 64;
  const int p = jcol0 >> 10;
  const int h = (jcol0 >> 6) & 15;
  // Q pre-scale: (1/sqrt(1024)) * log2(e), so attn can use exp2 directly.
  const float scale = (p == 0) ? 0.0450841149f : 1.0f;

  if (p < 2) {                               // Q, K: [h][m][d]
    bf16* base = qkv + (size_t)p * 4194304 + (size_t)h * 262144;
    #pragma unroll
    for (int mf = 0; mf < 4; ++mf)
      #pragma unroll
      for (int nf = 0; nf < 4; ++nf) {
        int d = nf * 16 + ln;
        #pragma unroll
        for (int r = 0; r < 4; ++r) {
          int m = m0 + wm * 64 + mf * 16 + quad * 4 + r;
          base[(size_t)m * 64 + d] = f2b(acc[mf][nf][r] * scale);
        }
      }
  } else {                                   // V transposed: [h][b][d][t]
    bf16* vb = qkv + (size_t)2 * 4194304 + (size_t)h * 262144;
    #pragma unroll
    for (int mf = 0; mf < 4; ++mf) {
      int mrow = m0 + wm * 64 + mf * 16 + quad * 4;
      int bi = mrow >> 11, t0 = mrow & 2047;
      #pragma unroll
      for (int nf = 0; nf < 4; ++nf) {
        int d = nf * 16 + ln;
        u64 pk = (u64)f2bu(acc[mf][nf][0]) |
                 ((u64)f2bu(acc[mf][nf][1]) << 16) |
                 ((u64)f2bu(acc[mf][nf][2]) << 32) |
                 ((u64)f2bu(acc[mf][nf][3]) << 48);
        *(u64*)(vb + (size_t)bi * 131072 + (size_t)d * 2048 + t0) = pk;
      }
    }
  }
}

// ---------------------------------------------------------------------------
// Kernel 2: causal flash attention, swapped-QK^T in-register softmax,
// QUADRANT-SPLIT waves (R13), k-loop unrolled x2 for compile-time buffers.
// Block = 4 waves, 64 q-rows, trips = mt+1 k-tiles. Wave w = (qh=w&1,
// kh=w>>1) computes the 32q x 32kv quadrant (8KB LDS reads/wave-tile).
// kv-half partials combined once per block via LDS scratch unioned over the
// dead K/V buffers. Staging kperm + slot swizzle identical to R12/R13.
// grid 1024 x 256thr, 4 blocks/CU; mt via 4-phase balanced table.
// ---------------------------------------------------------------------------
__global__ __launch_bounds__(256, 4) void attn_kernel(
    const bf16* __restrict__ qkv, bf16* __restrict__ att)
{
  union ShU {
    struct { bf16 K[2][64][64]; bf16 V[2][64][64]; } t;   // 32 KB tiles
    struct { float O[2][64][36]; float L[2][36]; } c;     // 18.7 KB combine
  };
  __shared__ __align__(16) ShU sh;

  const int fid = blockIdx.x;              // 0..1023
  const int j = fid >> 5;                  // 0..31
  const int jr = j & 7, jq = j >> 3;
  // 4-phase balanced mt table: {31-r, 8+r, 23-r, r}
  const int mt = (jq == 0) ? (31 - jr) : (jq == 1) ? (8 + jr)
               : (jq == 2) ? (23 - jr) : jr;
  const int grp = fid & 31;                // fid%8 == grp%8 -> same-grp same XCD
  const int b = grp >> 4, h = grp & 15;

  const int tid = threadIdx.x, w = tid >> 6, lane = tid & 63;
  const int ln = lane & 15, quad = lane >> 4;
  const int qh = w & 1, kh = w >> 1;       // quadrant ownership

  const bf16* qbase  = qkv + (size_t)h * 262144 + (size_t)b * 131072;
  const bf16* kbase  = qbase + 4194304;
  const bf16* vtbase = qbase + 8388608;    // [d][t], d-stride 2048

  // ---- staging lane constants (wave w stages LDS rows w*16..w*16+15) ----
  const int l8 = lane & 7, r8 = lane >> 3;
  const int slot = l8 ^ r8;                // swizzle: LDS[row][s] = G[row][s^(row&7)]
  const int p0 = w * 16 + r8, p1 = p0 + 8;
  // kperm(p): LDS row p holds K row (p&32) | ((p&12)<<1) | ((p&16)>>2) | (p&3)
  const int kp0 = (p0 & 32) | ((p0 & 12) << 1) | ((p0 & 16) >> 2) | (p0 & 3);
  const int kp1 = (p1 & 32) | ((p1 & 12) << 1) | ((p1 & 16) >> 2) | (p1 & 3);
  const bf16* gkp0 = kbase + kp0 * 64 + slot * 8;   // advanced by +4096/tile
  const bf16* gkp1 = kbase + kp1 * 64 + slot * 8;
  const bf16* gvp0 = vtbase + p0 * 2048 + slot * 8; // advanced by +64/tile
  const bf16* gvp1 = gvp0 + 8 * 2048;

  // ---- fragment-read lane constants (element offsets into [64][64]) ----
  const int sw = ln & 7;
  const int cc0 = ((quad    ) ^ sw) * 8;   // granule for d/kv half 0
  const int cc1 = ((quad + 4) ^ sw) * 8;   // granule for d/kv half 1
  const int cck = kh ? cc1 : cc0;          // V col granule for this kv-half
  const int krow0 = (kh * 32 + ln) * 64;   // K row offset, nfl=0 (elems)
  const int ka0 = krow0 + cc0, ka1 = krow0 + cc1;   // loop-invariant bases
  const int voff = ln * 64 + cck;

  v8bf vone;
  {
    unsigned short u = 0x3F80;             // 1.0 bf16
    __bf16 e = *reinterpret_cast<__bf16*>(&u);
    #pragma unroll
    for (int jj = 0; jj < 8; ++jj) vone[jj] = e;
  }
  const v4f vzero = {0.f, 0.f, 0.f, 0.f};
  const float NEG = -30000.0f;

  #define STAGE2(BUF) {                                          \
    load16_lds(gkp0, &sh.t.K[BUF][w * 16][0]);                   \
    load16_lds(gkp1, &sh.t.K[BUF][w * 16 + 8][0]);               \
    load16_lds(gvp0, &sh.t.V[BUF][w * 16][0]);                   \
    load16_lds(gvp1, &sh.t.V[BUF][w * 16 + 8][0]);               \
    gkp0 += 4096; gkp1 += 4096; gvp0 += 64; gvp1 += 64; }

  const int row0 = mt * 64;
  const int qrow = row0 + qh * 32;         // wave's q rows: qrow..qrow+31

  // Q fragments (B-operand): Q[qrow+mc*16+ln][ks*32 + quad*8 + j]
  v8bf aq[2][2];
  #pragma unroll
  for (int mc = 0; mc < 2; ++mc)
    #pragma unroll
    for (int ks = 0; ks < 2; ++ks)
      aq[mc][ks] = *(const v8bf*)(qbase +
          (size_t)(qrow + mc * 16 + ln) * 64 + ks * 32 + quad * 8);

  v4f o[2][4], lacc[2];
  #pragma unroll
  for (int mc = 0; mc < 2; ++mc) {
    lacc[mc] = vzero;
    #pragma unroll
    for (int dt = 0; dt < 4; ++dt) o[mc][dt] = vzero;
  }

  const int kb_end = mt;
  int kb = 0;
  STAGE2(0)                                // stage kb=0; ptrs now at kb=1

  // TILE(BUF): BUF is a compile-time literal -> ds_read addrs fold to
  // base VGPR + offset:imm; zero per-tile address VALU.
  #define TILE(BUF)                                                        \
  {                                                                        \
    __syncthreads();                       /* publishes BUF */             \
    const bf16* krB = &sh.t.K[BUF][0][0];                                  \
    const bf16* vrB = &sh.t.V[BUF][0][0];                                  \
    v8bf kf[2][2], vf[4];                                                  \
    kf[0][0] = *(const v8bf*)(krB + ka0);                                  \
    kf[1][0] = *(const v8bf*)(krB + ka1);                                  \
    kf[0][1] = *(const v8bf*)(krB + ka0 + 1024);                           \
    kf[1][1] = *(const v8bf*)(krB + ka1 + 1024);                           \
    vf[0] = *(const v8bf*)(vrB + voff);                                    \
    vf[1] = *(const v8bf*)(vrB + voff + 1024);                             \
    vf[2] = *(const v8bf*)(vrB + voff + 2048);                             \
    vf[3] = *(const v8bf*)(vrB + voff + 3072);                             \
    if (kb < kb_end) STAGE2(BUF ^ 1)                                       \
    _Pragma("unroll")                                                      \
    for (int mc = 0; mc < 2; ++mc) {                                       \
      __builtin_amdgcn_s_setprio(1);                                       \
      v4f s[2];                                                            \
      s[0] = vzero; s[1] = vzero;                                          \
      _Pragma("unroll")                                                    \
      for (int ks = 0; ks < 2; ++ks) {                                     \
        s[0] = MFMA16(kf[ks][0], aq[mc][ks], s[0]);                        \
        s[1] = MFMA16(kf[ks][1], aq[mc][ks], s[1]);                        \
      }                                                                    \
      __builtin_amdgcn_s_setprio(0);                                       \
      const int qg = qrow + mc * 16 + ln;                                  \
      if (kb == kb_end) {                  /* causal mask (diagonal) */    \
        _Pragma("unroll")                                                  \
        for (int nfl = 0; nfl < 2; ++nfl) {                                \
          const int kc = kb * 64 + kh * 32 + quad * 8 + nfl * 4;           \
          _Pragma("unroll")                                                \
          for (int r = 0; r < 4; ++r)                                      \
            if (kc + r > qg) s[nfl][r] = NEG;                              \
        }                                                                  \
      }                                                                    \
      float ex[2][4];                                                      \
      _Pragma("unroll")                                                    \
      for (int nfl = 0; nfl < 2; ++nfl)                                    \
        _Pragma("unroll")                                                  \
        for (int r = 0; r < 4; ++r)                                        \
          ex[nfl][r] = exp2f(s[nfl][r]);                                   \
      union { u32 uw[4]; v8bf v; } pu;                                     \
      _Pragma("unroll")                                                    \
      for (int nfl = 0; nfl < 2; ++nfl)                                    \
        _Pragma("unroll")                                                  \
        for (int wi = 0; wi < 2; ++wi)                                     \
          asm("v_cvt_pk_bf16_f32 %0, %1, %2"                               \
              : "=v"(pu.uw[nfl * 2 + wi])                                  \
              : "v"(ex[nfl][2 * wi]), "v"(ex[nfl][2 * wi + 1]));           \
      __builtin_amdgcn_s_setprio(1);                                       \
      lacc[mc] = MFMA16(pu.v, vone, lacc[mc]);                             \
      _Pragma("unroll")                                                    \
      for (int dt = 0; dt < 4; ++dt)                                       \
        o[mc][dt] = MFMA16(pu.v, vf[dt], o[mc][dt]);                       \
      __builtin_amdgcn_s_setprio(0);                                       \
    }                                                                      \
  }

  while (true) {
    TILE(0)
    if (kb >= kb_end) break;
    ++kb;
    TILE(1)
    if (kb >= kb_end) break;
    ++kb;
  }
  #undef TILE
  #undef STAGE2

  // ---- combine kv-half partials (kh=1 -> LDS, kh=0 adds) & epilogue ----
  __syncthreads();                         // all tile reads done; t is dead
  if (kh == 1) {
    #pragma unroll
    for (int mc = 0; mc < 2; ++mc) {
      #pragma unroll
      for (int dt = 0; dt < 4; ++dt)
        *(v4f*)&sh.c.O[qh][dt * 16 + ln][mc * 16 + quad * 4] = o[mc][dt];
      if (ln == 0)
        *(v4f*)&sh.c.L[qh][mc * 16 + quad * 4] = lacc[mc];
    }
  }
  __syncthreads();
  if (kh == 0) {
    #pragma unroll
    for (int mc = 0; mc < 2; ++mc) {
      v4f pl = *(const v4f*)&sh.c.L[qh][mc * 16 + quad * 4];
      v4f inv;
      #pragma unroll
      for (int r = 0; r < 4; ++r) inv[r] = 1.0f / (lacc[mc][r] + pl[r]);
      #pragma unroll
      for (int dt = 0; dt < 4; ++dt) {
        v4f po = *(const v4f*)&sh.c.O[qh][dt * 16 + ln][mc * 16 + quad * 4];
        #pragma unroll
        for (int r = 0; r < 4; ++r) {
          int m = b * 2048 + qrow + mc * 16 + quad * 4 + r;
          att[(size_t)m * 1024 + h * 64 + dt * 16 + ln] =
              f2b((o[mc][dt][r] + po[r]) * inv[r]);
        }
      }
    }
  }
}

// ---------------------------------------------------------------------------
// Kernel 3: output projection + bias, fp32 out. 128x64 tiles, BK=32,
// double-buffered, ONE barrier per k-step, slot-swizzled LDS (as kernel 1).
// grid (32 mt, 16 nt).
// ---------------------------------------------------------------------------
__global__ __launch_bounds__(256) void out_gemm_kernel(
    const bf16* __restrict__ att, const bf16* __restrict__ wot,
    const float* __restrict__ bo, float* __restrict__ out)
{
  __shared__ __align__(16) bf16 Ash[2][128][32];
  __shared__ __align__(16) bf16 Bsh[2][64][32];

  const int mt = blockIdx.x, nt = blockIdx.y;
  const int tid = threadIdx.x, w = tid >> 6, lane = tid & 63;
  const int ln = lane & 15, quad = lane >> 4;
  const int wm = w >> 1, wn = w & 1;
  const int m0 = mt * 128, n0 = nt * 64;

  const v4f vzero = {0.f, 0.f, 0.f, 0.f};
  v4f acc[4][2];
  #pragma unroll
  for (int mf = 0; mf < 4; ++mf)
    #pragma unroll
    for (int nf = 0; nf < 2; ++nf) acc[mf][nf] = vzero;

  // staging: linear LDS dest; global source segment pre-swizzled (see K1).
  const int srow = lane >> 2;
  const int sseg = ((lane & 3) ^ ((lane >> 3) & 3)) * 8;
  const bf16* ga = att + (size_t)(m0 + 32 * w + srow) * 1024 + sseg;
  const bf16* gb = wot + (size_t)(n0 + 16 * w + srow) * 1024 + sseg;

  const int fseg = (quad ^ ((ln >> 1) & 3)) * 8;

  {
    load16_lds(ga,             &Ash[0][32 * w][0]);
    load16_lds(ga + 16 * 1024, &Ash[0][32 * w + 16][0]);
    load16_lds(gb,             &Bsh[0][16 * w][0]);
  }

  for (int kt = 0; kt < 32; ++kt) {
    const int buf = kt & 1;
    __syncthreads();

    v8bf af[4], bfv[2];
    #pragma unroll
    for (int mf = 0; mf < 4; ++mf)
      af[mf] = *(const v8bf*)&Ash[buf][wm * 64 + mf * 16 + ln][fseg];
    #pragma unroll
    for (int nf = 0; nf < 2; ++nf)
      bfv[nf] = *(const v8bf*)&Bsh[buf][wn * 32 + nf * 16 + ln][fseg];

    if (kt < 31) {
      const int k0 = (kt + 1) * 32, nb = buf ^ 1;
      load16_lds(ga + k0,             &Ash[nb][32 * w][0]);
      load16_lds(ga + 16 * 1024 + k0, &Ash[nb][32 * w + 16][0]);
      load16_lds(gb + k0,             &Bsh[nb][16 * w][0]);
    }

    #pragma unroll
    for (int mf = 0; mf < 4; ++mf)
      #pragma unroll
      for (int nf = 0; nf < 2; ++nf)
        acc[mf][nf] = MFMA16(af[mf], bfv[nf], acc[mf][nf]);
  }

  #pragma unroll
  for (int nf = 0; nf < 2; ++nf) {
    int j = n0 + wn * 32 + nf * 16 + ln;
    float bias = bo[j];
    #pragma unroll
    for (int mf = 0; mf < 4; ++mf)
      #pragma unroll
      for (int r = 0; r < 4; ++r) {
        int m = m0 + wm * 64 + mf * 16 + quad * 4 + r;
        out[(size_t)m * 1024 + j] = acc[mf][nf][r] + bias;
      }
  }
}

extern "C" void kernel_launch(void* const* d_in, const int* in_sizes, int n_in,
                              void* d_out, int out_size, void* d_ws, size_t ws_size,
                              hipStream_t stream) {
  const float* x  = (const float*)d_in[0];
  const float* Wq = (const float*)d_in[1];
  const float* Wk = (const float*)d_in[2];
  const float* Wv = (const float*)d_in[3];
  const float* Wo = (const float*)d_in[4];
  const float* bo = (const float*)d_in[5];
  float* out = (float*)d_out;

  bf16* xb  = (bf16*)d_ws;
  bf16* wt  = xb + 4194304;
  bf16* wot = xb + 7340032;
  bf16* qkv = xb + 8388608;
  bf16* att = xb + 20971520;

  prep_kernel<<<6144, 256, 0, stream>>>(x, Wq, Wk, Wv, Wo, xb, wt, wot);
  qkv_gemm_kernel<<<dim3(32, 24), 256, 0, stream>>>(xb, wt, qkv);
  attn_kernel<<<1024, 256, 0, stream>>>(qkv, att);
  out_gemm_kernel<<<dim3(32, 16), 256, 0, stream>>>(att, wot, bo, out);
}

// Round 9
// 167.162 us; speedup vs baseline: 1.0140x; 1.0126x over previous
//
#include <hip/hip_runtime.h>
#include <hip/hip_bf16.h>

// MultiHead attention, MI355X/gfx950. fp32 in/out, bf16 MFMA internals.
// B=2, T=2048, C=1024, H=16, D=64.
// Round 16: both GEMMs get the R14 attn transform -- kt-loop UNROLLED x2 so
// the LDS buffer index is a compile-time literal (fragment ds_reads fold to
// hoisted base + offset:imm) and staging pointers are pure += induction.
// R14 qkv counters: VALUBusy 43% / MfmaUtil 21.5% at 44.4us = per-kt
// address recompute dominated (same pathology R14 fixed in attn, -38%).
// R15 lesson: the 3.15M bank-conflict cycles were only ~5us/CU upper bound
// (fix was correct but neutral); swizzle retained. attn/prep frozen.
//
// ws layout (bf16 elems):
//   xb  [4096][1024]            @ 0          (x as bf16)
//   wt  [3][16][64][1024]       @ 4194304    (= fused Bt [3072][1024])
//   wot [1024][1024]            @ 7340032    (Wo transposed, bf16)
//   qkv Q,K:[h][b*2048+t][d] Vt:[h][b][d][t] @ 8388608  (Q pre-scaled log2e/32)
//   att [4096][1024]            @ 20971520
// total 25165824 elems = 48 MB

typedef __hip_bfloat16 bf16;
typedef __bf16 v8bf __attribute__((ext_vector_type(8)));
typedef float  v4f  __attribute__((ext_vector_type(4)));
typedef unsigned long long u64;
typedef unsigned int u32;

#define MFMA16(a, b, c) __builtin_amdgcn_mfma_f32_16x16x32_bf16((a), (b), (c), 0, 0, 0)

__device__ __forceinline__ bf16 f2b(float x) { return __float2bfloat16(x); }
__device__ __forceinline__ __bf16 f2braw(float x) {
  bf16 t = __float2bfloat16(x);
  return *reinterpret_cast<__bf16*>(&t);
}
__device__ __forceinline__ unsigned short f2bu(float x) {
  bf16 t = __float2bfloat16(x);
  return *reinterpret_cast<unsigned short*>(&t);
}

// async global->LDS, 16B per lane; LDS dest = wave-uniform base + lane*16.
__device__ __forceinline__ void load16_lds(const bf16* gptr, const bf16* lptr) {
  __builtin_amdgcn_global_load_lds(
      (const __attribute__((address_space(1))) u32*)gptr,
      (__attribute__((address_space(3))) u32*)lptr, 16, 0, 0);
}

// ---------------------------------------------------------------------------
// Fused prep: [0,2048) cvt_x | [2048,5120) Wq/Wk/Wv transpose | [5120,6144) Wo.
// ---------------------------------------------------------------------------
__global__ __launch_bounds__(256) void prep_kernel(
    const float* __restrict__ x,
    const float* __restrict__ Wq, const float* __restrict__ Wk,
    const float* __restrict__ Wv, const float* __restrict__ Wo,
    bf16* __restrict__ xb, bf16* __restrict__ wt, bf16* __restrict__ wot)
{
  __shared__ float Lt[32][33];
  const int bid = blockIdx.x, tid = threadIdx.x;

  if (bid < 2048) {                        // x fp32 -> bf16
    size_t i = ((size_t)bid * 256 + tid) * 8;
    float4 f0 = *(const float4*)(x + i);
    float4 f1 = *(const float4*)(x + i + 4);
    v8bf v;
    v[0] = f2braw(f0.x); v[1] = f2braw(f0.y); v[2] = f2braw(f0.z); v[3] = f2braw(f0.w);
    v[4] = f2braw(f1.x); v[5] = f2braw(f1.y); v[6] = f2braw(f1.z); v[7] = f2braw(f1.w);
    *(v8bf*)(xb + i) = v;
    return;
  }
  const int tx = tid & 31, ty = tid >> 5;
  if (bid < 5120) {                        // Wq/Wk/Wv [h][1024][64] -> wt [z][64][1024]
    const int idx = bid - 2048;
    const int z = idx >> 6, rem = idx & 63;
    const int p = z >> 4, h = z & 15;
    const float* ib = ((p == 0) ? Wq : (p == 1) ? Wk : Wv) + (size_t)h * 65536;
    bf16* ob = wt + (size_t)z * 65536;
    const int j0 = (rem & 1) * 32, i0 = (rem >> 1) * 32;
    #pragma unroll
    for (int r = 0; r < 4; ++r)
      Lt[ty + 8 * r][tx] = ib[(size_t)(i0 + ty + 8 * r) * 64 + j0 + tx];
    __syncthreads();
    #pragma unroll
    for (int r = 0; r < 4; ++r)
      ob[(size_t)(j0 + ty + 8 * r) * 1024 + i0 + tx] = f2b(Lt[tx][ty + 8 * r]);
  } else {                                 // Wo [1024][1024] -> wot transposed
    const int idx = bid - 5120;
    const int j0 = (idx & 31) * 32, i0 = (idx >> 5) * 32;
    #pragma unroll
    for (int r = 0; r < 4; ++r)
      Lt[ty + 8 * r][tx] = Wo[(size_t)(i0 + ty + 8 * r) * 1024 + j0 + tx];
    __syncthreads();
    #pragma unroll
    for (int r = 0; r < 4; ++r)
      wot[(size_t)(j0 + ty + 8 * r) * 1024 + i0 + tx] = f2b(Lt[tx][ty + 8 * r]);
  }
}

// ---------------------------------------------------------------------------
// Kernel 1: fused QKV GEMM, M=4096 x N=3072, K=1024. 128x128 tile, BK=32,
// double-buffered LDS, ONE barrier per k-step, kt unrolled x2 (literal buf),
// staging via pointer induction. LDS slot-swizzled (R15). grid (32, 24).
// Epilogue scatters Q,K ([h][m][d], Q*log2e/32) and V transposed
// ([h][b][d][t]).
// ---------------------------------------------------------------------------
__global__ __launch_bounds__(256) void qkv_gemm_kernel(
    const bf16* __restrict__ xb, const bf16* __restrict__ wt,
    bf16* __restrict__ qkv)
{
  __shared__ __align__(16) bf16 Ash[2][128][32];
  __shared__ __align__(16) bf16 Bsh[2][128][32];

  const int mt = blockIdx.x, nt = blockIdx.y;
  const int tid = threadIdx.x, w = tid >> 6, lane = tid & 63;
  const int ln = lane & 15, quad = lane >> 4;
  const int wm = w >> 1, wn = w & 1;
  const int m0 = mt * 128, n0 = nt * 128;

  const v4f vzero = {0.f, 0.f, 0.f, 0.f};
  v4f acc[4][4];
  #pragma unroll
  for (int mf = 0; mf < 4; ++mf)
    #pragma unroll
    for (int nf = 0; nf < 4; ++nf) acc[mf][nf] = vzero;

  // staging: linear LDS dest; global source segment pre-swizzled.
  // row = 32w + (lane>>2); f(row) = (row>>1)&3 = (lane>>3)&3 (16-row inv).
  const int srow = lane >> 2;
  const int sseg = ((lane & 3) ^ ((lane >> 3) & 3)) * 8;
  const bf16* ga = xb + (size_t)(m0 + 32 * w + srow) * 1024 + sseg;
  const bf16* gb = wt + (size_t)(n0 + 32 * w + srow) * 1024 + sseg;

  // fragment-read slot: quad ^ f(row), f = (ln>>1)&3 (mf/nf-invariant).
  const int fseg = (quad ^ ((ln >> 1) & 3)) * 8;

  // prologue: stage k-step 0 into buf 0; pointers advance to kt=1.
  load16_lds(ga,             &Ash[0][32 * w][0]);
  load16_lds(ga + 16 * 1024, &Ash[0][32 * w + 16][0]);
  load16_lds(gb,             &Bsh[0][32 * w][0]);
  load16_lds(gb + 16 * 1024, &Bsh[0][32 * w + 16][0]);
  ga += 32; gb += 32;

  int kt = 0;
  // GTILE(BUF): BUF literal -> ds_read addrs fold to base + offset:imm.
  #define GTILE(BUF)                                                     \
  {                                                                      \
    __syncthreads();                       /* publishes BUF */           \
    v8bf af[4], bfv[4];                                                  \
    _Pragma("unroll")                                                    \
    for (int mf = 0; mf < 4; ++mf)                                       \
      af[mf] = *(const v8bf*)&Ash[BUF][wm * 64 + mf * 16 + ln][fseg];    \
    _Pragma("unroll")                                                    \
    for (int nf = 0; nf < 4; ++nf)                                       \
      bfv[nf] = *(const v8bf*)&Bsh[BUF][wn * 64 + nf * 16 + ln][fseg];   \
    if (kt < 31) {                         /* stage kt+1 into BUF^1 */   \
      load16_lds(ga,             &Ash[BUF ^ 1][32 * w][0]);              \
      load16_lds(ga + 16 * 1024, &Ash[BUF ^ 1][32 * w + 16][0]);         \
      load16_lds(gb,             &Bsh[BUF ^ 1][32 * w][0]);              \
      load16_lds(gb + 16 * 1024, &Bsh[BUF ^ 1][32 * w + 16][0]);         \
      ga += 32; gb += 32;                                                \
    }                                                                    \
    _Pragma("unroll")                                                    \
    for (int mf = 0; mf < 4; ++mf)                                       \
      _Pragma("unroll")                                                  \
      for (int nf = 0; nf < 4; ++nf)                                     \
        acc[mf][nf] = MFMA16(af[mf], bfv[nf], acc[mf][nf]);              \
    ++kt;                                                                \
  }

  #pragma unroll 1
  for (int it = 0; it < 16; ++it) {
    GTILE(0)
    GTILE(1)
  }
  #undef GTILE

  const int jcol0 = n0 + wn * 64;
  const int p = jcol0 >> 10;
  const int h = (jcol0 >> 6) & 15;
  // Q pre-scale: (1/sqrt(1024)) * log2(e), so attn can use exp2 directly.
  const float scale = (p == 0) ? 0.0450841149f : 1.0f;

  if (p < 2) {                               // Q, K: [h][m][d]
    bf16* base = qkv + (size_t)p * 4194304 + (size_t)h * 262144;
    #pragma unroll
    for (int mf = 0; mf < 4; ++mf)
      #pragma unroll
      for (int nf = 0; nf < 4; ++nf) {
        int d = nf * 16 + ln;
        #pragma unroll
        for (int r = 0; r < 4; ++r) {
          int m = m0 + wm * 64 + mf * 16 + quad * 4 + r;
          base[(size_t)m * 64 + d] = f2b(acc[mf][nf][r] * scale);
        }
      }
  } else {                                   // V transposed: [h][b][d][t]
    bf16* vb = qkv + (size_t)2 * 4194304 + (size_t)h * 262144;
    #pragma unroll
    for (int mf = 0; mf < 4; ++mf) {
      int mrow = m0 + wm * 64 + mf * 16 + quad * 4;
      int bi = mrow >> 11, t0 = mrow & 2047;
      #pragma unroll
      for (int nf = 0; nf < 4; ++nf) {
        int d = nf * 16 + ln;
        u64 pk = (u64)f2bu(acc[mf][nf][0]) |
                 ((u64)f2bu(acc[mf][nf][1]) << 16) |
                 ((u64)f2bu(acc[mf][nf][2]) << 32) |
                 ((u64)f2bu(acc[mf][nf][3]) << 48);
        *(u64*)(vb + (size_t)bi * 131072 + (size_t)d * 2048 + t0) = pk;
      }
    }
  }
}

// ---------------------------------------------------------------------------
// Kernel 2: causal flash attention, swapped-QK^T in-register softmax,
// QUADRANT-SPLIT waves (R13), k-loop unrolled x2 for compile-time buffers.
// Block = 4 waves, 64 q-rows, trips = mt+1 k-tiles. Wave w = (qh=w&1,
// kh=w>>1) computes the 32q x 32kv quadrant (8KB LDS reads/wave-tile).
// kv-half partials combined once per block via LDS scratch unioned over the
// dead K/V buffers. Staging kperm + slot swizzle identical to R12/R13.
// grid 1024 x 256thr, 4 blocks/CU; mt via 4-phase balanced table.
// ---------------------------------------------------------------------------
__global__ __launch_bounds__(256, 4) void attn_kernel(
    const bf16* __restrict__ qkv, bf16* __restrict__ att)
{
  union ShU {
    struct { bf16 K[2][64][64]; bf16 V[2][64][64]; } t;   // 32 KB tiles
    struct { float O[2][64][36]; float L[2][36]; } c;     // 18.7 KB combine
  };
  __shared__ __align__(16) ShU sh;

  const int fid = blockIdx.x;              // 0..1023
  const int j = fid >> 5;                  // 0..31
  const int jr = j & 7, jq = j >> 3;
  // 4-phase balanced mt table: {31-r, 8+r, 23-r, r}
  const int mt = (jq == 0) ? (31 - jr) : (jq == 1) ? (8 + jr)
               : (jq == 2) ? (23 - jr) : jr;
  const int grp = fid & 31;                // fid%8 == grp%8 -> same-grp same XCD
  const int b = grp >> 4, h = grp & 15;

  const int tid = threadIdx.x, w = tid >> 6, lane = tid & 63;
  const int ln = lane & 15, quad = lane >> 4;
  const int qh = w & 1, kh = w >> 1;       // quadrant ownership

  const bf16* qbase  = qkv + (size_t)h * 262144 + (size_t)b * 131072;
  const bf16* kbase  = qbase + 4194304;
  const bf16* vtbase = qbase + 8388608;    // [d][t], d-stride 2048

  // ---- staging lane constants (wave w stages LDS rows w*16..w*16+15) ----
  const int l8 = lane & 7, r8 = lane >> 3;
  const int slot = l8 ^ r8;                // swizzle: LDS[row][s] = G[row][s^(row&7)]
  const int p0 = w * 16 + r8, p1 = p0 + 8;
  // kperm(p): LDS row p holds K row (p&32) | ((p&12)<<1) | ((p&16)>>2) | (p&3)
  const int kp0 = (p0 & 32) | ((p0 & 12) << 1) | ((p0 & 16) >> 2) | (p0 & 3);
  const int kp1 = (p1 & 32) | ((p1 & 12) << 1) | ((p1 & 16) >> 2) | (p1 & 3);
  const bf16* gkp0 = kbase + kp0 * 64 + slot * 8;   // advanced by +4096/tile
  const bf16* gkp1 = kbase + kp1 * 64 + slot * 8;
  const bf16* gvp0 = vtbase + p0 * 2048 + slot * 8; // advanced by +64/tile
  const bf16* gvp1 = gvp0 + 8 * 2048;

  // ---- fragment-read lane constants (element offsets into [64][64]) ----
  const int sw = ln & 7;
  const int cc0 = ((quad    ) ^ sw) * 8;   // granule for d/kv half 0
  const int cc1 = ((quad + 4) ^ sw) * 8;   // granule for d/kv half 1
  const int cck = kh ? cc1 : cc0;          // V col granule for this kv-half
  const int krow0 = (kh * 32 + ln) * 64;   // K row offset, nfl=0 (elems)
  const int ka0 = krow0 + cc0, ka1 = krow0 + cc1;   // loop-invariant bases
  const int voff = ln * 64 + cck;

  v8bf vone;
  {
    unsigned short u = 0x3F80;             // 1.0 bf16
    __bf16 e = *reinterpret_cast<__bf16*>(&u);
    #pragma unroll
    for (int jj = 0; jj < 8; ++jj) vone[jj] = e;
  }
  const v4f vzero = {0.f, 0.f, 0.f, 0.f};
  const float NEG = -30000.0f;

  #define STAGE2(BUF) {                                          \
    load16_lds(gkp0, &sh.t.K[BUF][w * 16][0]);                   \
    load16_lds(gkp1, &sh.t.K[BUF][w * 16 + 8][0]);               \
    load16_lds(gvp0, &sh.t.V[BUF][w * 16][0]);                   \
    load16_lds(gvp1, &sh.t.V[BUF][w * 16 + 8][0]);               \
    gkp0 += 4096; gkp1 += 4096; gvp0 += 64; gvp1 += 64; }

  const int row0 = mt * 64;
  const int qrow = row0 + qh * 32;         // wave's q rows: qrow..qrow+31

  // Q fragments (B-operand): Q[qrow+mc*16+ln][ks*32 + quad*8 + j]
  v8bf aq[2][2];
  #pragma unroll
  for (int mc = 0; mc < 2; ++mc)
    #pragma unroll
    for (int ks = 0; ks < 2; ++ks)
      aq[mc][ks] = *(const v8bf*)(qbase +
          (size_t)(qrow + mc * 16 + ln) * 64 + ks * 32 + quad * 8);

  v4f o[2][4], lacc[2];
  #pragma unroll
  for (int mc = 0; mc < 2; ++mc) {
    lacc[mc] = vzero;
    #pragma unroll
    for (int dt = 0; dt < 4; ++dt) o[mc][dt] = vzero;
  }

  const int kb_end = mt;
  int kb = 0;
  STAGE2(0)                                // stage kb=0; ptrs now at kb=1

  // TILE(BUF): BUF is a compile-time literal -> ds_read addrs fold to
  // base VGPR + offset:imm; zero per-tile address VALU.
  #define TILE(BUF)                                                        \
  {                                                                        \
    __syncthreads();                       /* publishes BUF */             \
    const bf16* krB = &sh.t.K[BUF][0][0];                                  \
    const bf16* vrB = &sh.t.V[BUF][0][0];                                  \
    v8bf kf[2][2], vf[4];                                                  \
    kf[0][0] = *(const v8bf*)(krB + ka0);                                  \
    kf[1][0] = *(const v8bf*)(krB + ka1);                                  \
    kf[0][1] = *(const v8bf*)(krB + ka0 + 1024);                           \
    kf[1][1] = *(const v8bf*)(krB + ka1 + 1024);                           \
    vf[0] = *(const v8bf*)(vrB + voff);                                    \
    vf[1] = *(const v8bf*)(vrB + voff + 1024);                             \
    vf[2] = *(const v8bf*)(vrB + voff + 2048);                             \
    vf[3] = *(const v8bf*)(vrB + voff + 3072);                             \
    if (kb < kb_end) STAGE2(BUF ^ 1)                                       \
    _Pragma("unroll")                                                      \
    for (int mc = 0; mc < 2; ++mc) {                                       \
      __builtin_amdgcn_s_setprio(1);                                       \
      v4f s[2];                                                            \
      s[0] = vzero; s[1] = vzero;                                          \
      _Pragma("unroll")                                                    \
      for (int ks = 0; ks < 2; ++ks) {                                     \
        s[0] = MFMA16(kf[ks][0], aq[mc][ks], s[0]);                        \
        s[1] = MFMA16(kf[ks][1], aq[mc][ks], s[1]);                        \
      }                                                                    \
      __builtin_amdgcn_s_setprio(0);                                       \
      const int qg = qrow + mc * 16 + ln;                                  \
      if (kb == kb_end) {                  /* causal mask (diagonal) */    \
        _Pragma("unroll")                                                  \
        for (int nfl = 0; nfl < 2; ++nfl) {                                \
          const int kc = kb * 64 + kh * 32 + quad * 8 + nfl * 4;           \
          _Pragma("unroll")                                                \
          for (int r = 0; r < 4; ++r)                                      \
            if (kc + r > qg) s[nfl][r] = NEG;                              \
        }                                                                  \
      }                                                                    \
      float ex[2][4];                                                      \
      _Pragma("unroll")                                                    \
      for (int nfl = 0; nfl < 2; ++nfl)                                    \
        _Pragma("unroll")                                                  \
        for (int r = 0; r < 4; ++r)                                        \
          ex[nfl][r] = exp2f(s[nfl][r]);                                   \
      union { u32 uw[4]; v8bf v; } pu;                                     \
      _Pragma("unroll")                                                    \
      for (int nfl = 0; nfl < 2; ++nfl)                                    \
        _Pragma("unroll")                                                  \
        for (int wi = 0; wi < 2; ++wi)                                     \
          asm("v_cvt_pk_bf16_f32 %0, %1, %2"                               \
              : "=v"(pu.uw[nfl * 2 + wi])                                  \
              : "v"(ex[nfl][2 * wi]), "v"(ex[nfl][2 * wi + 1]));           \
      __builtin_amdgcn_s_setprio(1);                                       \
      lacc[mc] = MFMA16(pu.v, vone, lacc[mc]);                             \
      _Pragma("unroll")                                                    \
      for (int dt = 0; dt < 4; ++dt)                                       \
        o[mc][dt] = MFMA16(pu.v, vf[dt], o[mc][dt]);                       \
      __builtin_amdgcn_s_setprio(0);                                       \
    }                                                                      \
  }

  while (true) {
    TILE(0)
    if (kb >= kb_end) break;
    ++kb;
    TILE(1)
    if (kb >= kb_end) break;
    ++kb;
  }
  #undef TILE
  #undef STAGE2

  // ---- combine kv-half partials (kh=1 -> LDS, kh=0 adds) & epilogue ----
  __syncthreads();                         // all tile reads done; t is dead
  if (kh == 1) {
    #pragma unroll
    for (int mc = 0; mc < 2; ++mc) {
      #pragma unroll
      for (int dt = 0; dt < 4; ++dt)
        *(v4f*)&sh.c.O[qh][dt * 16 + ln][mc * 16 + quad * 4] = o[mc][dt];
      if (ln == 0)
        *(v4f*)&sh.c.L[qh][mc * 16 + quad * 4] = lacc[mc];
    }
  }
  __syncthreads();
  if (kh == 0) {
    #pragma unroll
    for (int mc = 0; mc < 2; ++mc) {
      v4f pl = *(const v4f*)&sh.c.L[qh][mc * 16 + quad * 4];
      v4f inv;
      #pragma unroll
      for (int r = 0; r < 4; ++r) inv[r] = 1.0f / (lacc[mc][r] + pl[r]);
      #pragma unroll
      for (int dt = 0; dt < 4; ++dt) {
        v4f po = *(const v4f*)&sh.c.O[qh][dt * 16 + ln][mc * 16 + quad * 4];
        #pragma unroll
        for (int r = 0; r < 4; ++r) {
          int m = b * 2048 + qrow + mc * 16 + quad * 4 + r;
          att[(size_t)m * 1024 + h * 64 + dt * 16 + ln] =
              f2b((o[mc][dt][r] + po[r]) * inv[r]);
        }
      }
    }
  }
}

// ---------------------------------------------------------------------------
// Kernel 3: output projection + bias, fp32 out. 128x64 tiles, BK=32,
// double-buffered, ONE barrier per k-step, kt unrolled x2 (literal buf),
// staging via pointer induction, slot-swizzled LDS. grid (32, 16).
// ---------------------------------------------------------------------------
__global__ __launch_bounds__(256) void out_gemm_kernel(
    const bf16* __restrict__ att, const bf16* __restrict__ wot,
    const float* __restrict__ bo, float* __restrict__ out)
{
  __shared__ __align__(16) bf16 Ash[2][128][32];
  __shared__ __align__(16) bf16 Bsh[2][64][32];

  const int mt = blockIdx.x, nt = blockIdx.y;
  const int tid = threadIdx.x, w = tid >> 6, lane = tid & 63;
  const int ln = lane & 15, quad = lane >> 4;
  const int wm = w >> 1, wn = w & 1;
  const int m0 = mt * 128, n0 = nt * 64;

  const v4f vzero = {0.f, 0.f, 0.f, 0.f};
  v4f acc[4][2];
  #pragma unroll
  for (int mf = 0; mf < 4; ++mf)
    #pragma unroll
    for (int nf = 0; nf < 2; ++nf) acc[mf][nf] = vzero;

  // staging: linear LDS dest; global source segment pre-swizzled (see K1).
  const int srow = lane >> 2;
  const int sseg = ((lane & 3) ^ ((lane >> 3) & 3)) * 8;
  const bf16* ga = att + (size_t)(m0 + 32 * w + srow) * 1024 + sseg;
  const bf16* gb = wot + (size_t)(n0 + 16 * w + srow) * 1024 + sseg;

  const int fseg = (quad ^ ((ln >> 1) & 3)) * 8;

  load16_lds(ga,             &Ash[0][32 * w][0]);
  load16_lds(ga + 16 * 1024, &Ash[0][32 * w + 16][0]);
  load16_lds(gb,             &Bsh[0][16 * w][0]);
  ga += 32; gb += 32;

  int kt = 0;
  #define OTILE(BUF)                                                     \
  {                                                                      \
    __syncthreads();                                                     \
    v8bf af[4], bfv[2];                                                  \
    _Pragma("unroll")                                                    \
    for (int mf = 0; mf < 4; ++mf)                                       \
      af[mf] = *(const v8bf*)&Ash[BUF][wm * 64 + mf * 16 + ln][fseg];    \
    _Pragma("unroll")                                                    \
    for (int nf = 0; nf < 2; ++nf)                                       \
      bfv[nf] = *(const v8bf*)&Bsh[BUF][wn * 32 + nf * 16 + ln][fseg];   \
    if (kt < 31) {                                                       \
      load16_lds(ga,             &Ash[BUF ^ 1][32 * w][0]);              \
      load16_lds(ga + 16 * 1024, &Ash[BUF ^ 1][32 * w + 16][0]);         \
      load16_lds(gb,             &Bsh[BUF ^ 1][16 * w][0]);              \
      ga += 32; gb += 32;                                                \
    }                                                                    \
    _Pragma("unroll")                                                    \
    for (int mf = 0; mf < 4; ++mf)                                       \
      _Pragma("unroll")                                                  \
      for (int nf = 0; nf < 2; ++nf)                                     \
        acc[mf][nf] = MFMA16(af[mf], bfv[nf], acc[mf][nf]);              \
    ++kt;                                                                \
  }

  #pragma unroll 1
  for (int it = 0; it < 16; ++it) {
    OTILE(0)
    OTILE(1)
  }
  #undef OTILE

  #pragma unroll
  for (int nf = 0; nf < 2; ++nf) {
    int j = n0 + wn * 32 + nf * 16 + ln;
    float bias = bo[j];
    #pragma unroll
    for (int mf = 0; mf < 4; ++mf)
      #pragma unroll
      for (int r = 0; r < 4; ++r) {
        int m = m0 + wm * 64 + mf * 16 + quad * 4 + r;
        out[(size_t)m * 1024 + j] = acc[mf][nf][r] + bias;
      }
  }
}

extern "C" void kernel_launch(void* const* d_in, const int* in_sizes, int n_in,
                              void* d_out, int out_size, void* d_ws, size_t ws_size,
                              hipStream_t stream) {
  const float* x  = (const float*)d_in[0];
  const float* Wq = (const float*)d_in[1];
  const float* Wk = (const float*)d_in[2];
  const float* Wv = (const float*)d_in[3];
  const float* Wo = (const float*)d_in[4];
  const float* bo = (const float*)d_in[5];
  float* out = (float*)d_out;

  bf16* xb  = (bf16*)d_ws;
  bf16* wt  = xb + 4194304;
  bf16* wot = xb + 7340032;
  bf16* qkv = xb + 8388608;
  bf16* att = xb + 20971520;

  prep_kernel<<<6144, 256, 0, stream>>>(x, Wq, Wk, Wv, Wo, xb, wt, wot);
  qkv_gemm_kernel<<<dim3(32, 24), 256, 0, stream>>>(xb, wt, qkv);
  attn_kernel<<<1024, 256, 0, stream>>>(qkv, att);
  out_gemm_kernel<<<dim3(32, 16), 256, 0, stream>>>(att, wot, bo, out);
}

// Round 10
// 165.529 us; speedup vs baseline: 1.0240x; 1.0099x over previous
//
#include <hip/hip_runtime.h>
#include <hip/hip_bf16.h>

// MultiHead attention, MI355X/gfx950. fp32 in/out, bf16 MFMA internals.
// B=2, T=2048, C=1024, H=16, D=64.
// Round 17: qkv GEMM rebuilt with T3/T4 structure. R14 counters re-read:
// VALUBusy includes MFMA issue; the real binders were the LDS port (46%)
// and per-barrier vmcnt(0) drains. New qkv: 256x192 tile (grid 16x16 =
// EXACTLY 1 block/CU), 512 thr / 8 waves (4Mx2N, wave-tile 64x96), BK=32,
// THREE LDS buffers (96KB) -> 2-tile-deep prefetch with uniform counted
// s_waitcnt vmcnt(4) at every barrier (never 0 in the loop): tile t's
// loads were issued 2 tiles ago (aged > HBM latency, wait ~free); the next
// 8 loads stay in flight ACROSS the barrier. Safety proof: STAGE(t+2)
// writes buf (t-1)%3 whose reads finished before any wave crossed barrier
// t (lgkmcnt(0) before every barrier). Unrolled x3 -> literal buffers,
// loop body t-invariant (pure pointer induction). B-tile padded to 256
// LDS rows so all 8 waves issue exactly 4 loads/step (uniform vmcnt).
// R15 slot-swizzle kept. attn (R14) / out_gemm (R16) / prep frozen.
//
// ws layout (bf16 elems):
//   xb  [4096][1024]            @ 0          (x as bf16)
//   wt  [3][16][64][1024]       @ 4194304    (= fused Bt [3072][1024])
//   wot [1024][1024]            @ 7340032    (Wo transposed, bf16)
//   qkv Q,K:[h][b*2048+t][d] Vt:[h][b][d][t] @ 8388608  (Q pre-scaled log2e/32)
//   att [4096][1024]            @ 20971520
// total 25165824 elems = 48 MB

typedef __hip_bfloat16 bf16;
typedef __bf16 v8bf __attribute__((ext_vector_type(8)));
typedef float  v4f  __attribute__((ext_vector_type(4)));
typedef unsigned long long u64;
typedef unsigned int u32;

#define MFMA16(a, b, c) __builtin_amdgcn_mfma_f32_16x16x32_bf16((a), (b), (c), 0, 0, 0)

__device__ __forceinline__ bf16 f2b(float x) { return __float2bfloat16(x); }
__device__ __forceinline__ __bf16 f2braw(float x) {
  bf16 t = __float2bfloat16(x);
  return *reinterpret_cast<__bf16*>(&t);
}
__device__ __forceinline__ unsigned short f2bu(float x) {
  bf16 t = __float2bfloat16(x);
  return *reinterpret_cast<unsigned short*>(&t);
}

// async global->LDS, 16B per lane; LDS dest = wave-uniform base + lane*16.
__device__ __forceinline__ void load16_lds(const bf16* gptr, const bf16* lptr) {
  __builtin_amdgcn_global_load_lds(
      (const __attribute__((address_space(1))) u32*)gptr,
      (__attribute__((address_space(3))) u32*)lptr, 16, 0, 0);
}

// ---------------------------------------------------------------------------
// Fused prep: [0,2048) cvt_x | [2048,5120) Wq/Wk/Wv transpose | [5120,6144) Wo.
// ---------------------------------------------------------------------------
__global__ __launch_bounds__(256) void prep_kernel(
    const float* __restrict__ x,
    const float* __restrict__ Wq, const float* __restrict__ Wk,
    const float* __restrict__ Wv, const float* __restrict__ Wo,
    bf16* __restrict__ xb, bf16* __restrict__ wt, bf16* __restrict__ wot)
{
  __shared__ float Lt[32][33];
  const int bid = blockIdx.x, tid = threadIdx.x;

  if (bid < 2048) {                        // x fp32 -> bf16
    size_t i = ((size_t)bid * 256 + tid) * 8;
    float4 f0 = *(const float4*)(x + i);
    float4 f1 = *(const float4*)(x + i + 4);
    v8bf v;
    v[0] = f2braw(f0.x); v[1] = f2braw(f0.y); v[2] = f2braw(f0.z); v[3] = f2braw(f0.w);
    v[4] = f2braw(f1.x); v[5] = f2braw(f1.y); v[6] = f2braw(f1.z); v[7] = f2braw(f1.w);
    *(v8bf*)(xb + i) = v;
    return;
  }
  const int tx = tid & 31, ty = tid >> 5;
  if (bid < 5120) {                        // Wq/Wk/Wv [h][1024][64] -> wt [z][64][1024]
    const int idx = bid - 2048;
    const int z = idx >> 6, rem = idx & 63;
    const int p = z >> 4, h = z & 15;
    const float* ib = ((p == 0) ? Wq : (p == 1) ? Wk : Wv) + (size_t)h * 65536;
    bf16* ob = wt + (size_t)z * 65536;
    const int j0 = (rem & 1) * 32, i0 = (rem >> 1) * 32;
    #pragma unroll
    for (int r = 0; r < 4; ++r)
      Lt[ty + 8 * r][tx] = ib[(size_t)(i0 + ty + 8 * r) * 64 + j0 + tx];
    __syncthreads();
    #pragma unroll
    for (int r = 0; r < 4; ++r)
      ob[(size_t)(j0 + ty + 8 * r) * 1024 + i0 + tx] = f2b(Lt[tx][ty + 8 * r]);
  } else {                                 // Wo [1024][1024] -> wot transposed
    const int idx = bid - 5120;
    const int j0 = (idx & 31) * 32, i0 = (idx >> 5) * 32;
    #pragma unroll
    for (int r = 0; r < 4; ++r)
      Lt[ty + 8 * r][tx] = Wo[(size_t)(i0 + ty + 8 * r) * 1024 + j0 + tx];
    __syncthreads();
    #pragma unroll
    for (int r = 0; r < 4; ++r)
      wot[(size_t)(j0 + ty + 8 * r) * 1024 + i0 + tx] = f2b(Lt[tx][ty + 8 * r]);
  }
}

// ---------------------------------------------------------------------------
// Kernel 1: fused QKV GEMM, M=4096 x N=3072, K=1024.
// 256x192 tile, BK=32, grid (16,16) = 1 block/CU. 512 thr = 8 waves (4Mx2N),
// wave-tile 64x96 (acc[4][6]). 3 LDS buffers, 2-tile prefetch, counted
// vmcnt(4) at every barrier (vmcnt(0) only at the last step). Slot-swizzled
// LDS (R15). Epilogue scatters Q,K ([h][m][d], Q*log2e/32) and V transposed
// ([h][b][d][t]); tiles straddle the Q|K|V boundary so p/h resolved per nf.
// ---------------------------------------------------------------------------
__global__ __launch_bounds__(512, 2) void qkv_gemm_kernel(
    const bf16* __restrict__ xb, const bf16* __restrict__ wt,
    bf16* __restrict__ qkv)
{
  __shared__ __align__(16) bf16 Ash[3][256][32];
  __shared__ __align__(16) bf16 Bsh[3][256][32];   // rows 192..255 = pad

  const int mt = blockIdx.x, nt = blockIdx.y;
  const int tid = threadIdx.x, wid = tid >> 6, lane = tid & 63;
  const int ln = lane & 15, quad = lane >> 4;
  const int wm = wid >> 1, wn = wid & 1;           // 4Mx2N wave grid
  const int m0 = mt * 256, n0 = nt * 192;

  const v4f vzero = {0.f, 0.f, 0.f, 0.f};
  v4f acc[4][6];
  #pragma unroll
  for (int mf = 0; mf < 4; ++mf)
    #pragma unroll
    for (int nf = 0; nf < 6; ++nf) acc[mf][nf] = vzero;

  // staging: linear LDS dest; global source segment pre-swizzled (R15):
  // LDS[row][s] = G[row][s ^ ((row>>1)&3)]; for row = wid*32 + srow the
  // XOR term is (lane>>3)&3 (invariant under +16-row shifts).
  const int srow = lane >> 2;
  const int sseg = ((lane & 3) ^ ((lane >> 3) & 3)) * 8;
  const int arow = wid * 32 + srow;
  const int br0 = wid * 32 + srow,  brow0 = (br0 < 192) ? br0 : 191;   // pad clamp
  const int br1 = wid * 32 + 16 + srow, brow1 = (br1 < 192) ? br1 : 191;
  const bf16* ga  = xb + (size_t)(m0 + arow) * 1024 + sseg;
  const bf16* gb0 = wt + (size_t)(n0 + brow0) * 1024 + sseg;
  const bf16* gb1 = wt + (size_t)(n0 + brow1) * 1024 + sseg;

  // fragment-read slot: quad ^ ((ln>>1)&3) (mf/nf/wave invariant).
  const int fseg = (quad ^ ((ln >> 1) & 3)) * 8;

  // 4 loads per wave per step (uniform across waves -> uniform vmcnt).
  #define QSTAGE(BUF) {                                          \
    load16_lds(ga,              &Ash[BUF][wid * 32][0]);         \
    load16_lds(ga + 16 * 1024,  &Ash[BUF][wid * 32 + 16][0]);    \
    load16_lds(gb0,             &Bsh[BUF][wid * 32][0]);         \
    load16_lds(gb1,             &Bsh[BUF][wid * 32 + 16][0]);    \
    ga += 32; gb0 += 32; gb1 += 32; }

  // prologue: tiles 0,1 staged; 8 loads in flight.
  QSTAGE(0)
  QSTAGE(1)

  // QSTEP: counted-vmcnt barrier; reads buf (literal); prefetches t+2 into
  // (BUF+2)%3 (compile-time). Safety: (BUF+2)%3 == (t-1)%3, whose reads
  // completed before every wave crossed this barrier (lgkmcnt(0) below).
  #define QSTEP(BUF, VM, DOSTAGE)                                          \
  {                                                                        \
    asm volatile("s_waitcnt vmcnt(" #VM ") lgkmcnt(0)" ::: "memory");      \
    __builtin_amdgcn_s_barrier();                                          \
    __builtin_amdgcn_sched_barrier(0);                                     \
    v8bf af[4], bfv[6];                                                    \
    _Pragma("unroll")                                                      \
    for (int mf = 0; mf < 4; ++mf)                                         \
      af[mf] = *(const v8bf*)&Ash[BUF][wm * 64 + mf * 16 + ln][fseg];      \
    _Pragma("unroll")                                                      \
    for (int nf = 0; nf < 6; ++nf)                                         \
      bfv[nf] = *(const v8bf*)&Bsh[BUF][wn * 96 + nf * 16 + ln][fseg];     \
    if (DOSTAGE) QSTAGE((BUF + 2) % 3)                                     \
    __builtin_amdgcn_s_setprio(1);                                         \
    _Pragma("unroll")                                                      \
    for (int mf = 0; mf < 4; ++mf)                                         \
      _Pragma("unroll")                                                    \
      for (int nf = 0; nf < 6; ++nf)                                       \
        acc[mf][nf] = MFMA16(af[mf], bfv[nf], acc[mf][nf]);                \
    __builtin_amdgcn_s_setprio(0);                                         \
  }

  // main loop: steps t=0..29 (buf = t%3), body is t-invariant.
  #pragma unroll 1
  for (int it = 0; it < 10; ++it) {
    QSTEP(0, 4, 1)
    QSTEP(1, 4, 1)
    QSTEP(2, 4, 1)
  }
  // tail: t=30 (buf0, t31 still in flight -> vmcnt(4)); t=31 (buf1, drain).
  QSTEP(0, 4, 0)
  QSTEP(1, 0, 0)
  #undef QSTEP
  #undef QSTAGE

  // epilogue: 192-wide tiles straddle Q|K|V boundaries -> resolve per nf.
  #pragma unroll
  for (int nf = 0; nf < 6; ++nf) {
    const int j = n0 + wn * 96 + nf * 16 + ln;     // global fused column
    const int p = j >> 10;
    const int h = (j >> 6) & 15;
    const int d = j & 63;
    if (p < 2) {                                   // Q, K: [h][m][d]
      const float scale = (p == 0) ? 0.0450841149f : 1.0f;  // log2e/32
      bf16* base = qkv + (size_t)p * 4194304 + (size_t)h * 262144;
      #pragma unroll
      for (int mf = 0; mf < 4; ++mf)
        #pragma unroll
        for (int r = 0; r < 4; ++r) {
          int m = m0 + wm * 64 + mf * 16 + quad * 4 + r;
          base[(size_t)m * 64 + d] = f2b(acc[mf][nf][r] * scale);
        }
    } else {                                       // V transposed: [h][b][d][t]
      bf16* vb = qkv + (size_t)2 * 4194304 + (size_t)h * 262144;
      #pragma unroll
      for (int mf = 0; mf < 4; ++mf) {
        int mrow = m0 + wm * 64 + mf * 16 + quad * 4;
        int bi = mrow >> 11, t0 = mrow & 2047;
        u64 pk = (u64)f2bu(acc[mf][nf][0]) |
                 ((u64)f2bu(acc[mf][nf][1]) << 16) |
                 ((u64)f2bu(acc[mf][nf][2]) << 32) |
                 ((u64)f2bu(acc[mf][nf][3]) << 48);
        *(u64*)(vb + (size_t)bi * 131072 + (size_t)d * 2048 + t0) = pk;
      }
    }
  }
}

// ---------------------------------------------------------------------------
// Kernel 2: causal flash attention, swapped-QK^T in-register softmax,
// QUADRANT-SPLIT waves (R13), k-loop unrolled x2 for compile-time buffers.
// Block = 4 waves, 64 q-rows, trips = mt+1 k-tiles. Wave w = (qh=w&1,
// kh=w>>1) computes the 32q x 32kv quadrant (8KB LDS reads/wave-tile).
// kv-half partials combined once per block via LDS scratch unioned over the
// dead K/V buffers. Staging kperm + slot swizzle identical to R12/R13.
// grid 1024 x 256thr, 4 blocks/CU; mt via 4-phase balanced table.
// ---------------------------------------------------------------------------
__global__ __launch_bounds__(256, 4) void attn_kernel(
    const bf16* __restrict__ qkv, bf16* __restrict__ att)
{
  union ShU {
    struct { bf16 K[2][64][64]; bf16 V[2][64][64]; } t;   // 32 KB tiles
    struct { float O[2][64][36]; float L[2][36]; } c;     // 18.7 KB combine
  };
  __shared__ __align__(16) ShU sh;

  const int fid = blockIdx.x;              // 0..1023
  const int j = fid >> 5;                  // 0..31
  const int jr = j & 7, jq = j >> 3;
  // 4-phase balanced mt table: {31-r, 8+r, 23-r, r}
  const int mt = (jq == 0) ? (31 - jr) : (jq == 1) ? (8 + jr)
               : (jq == 2) ? (23 - jr) : jr;
  const int grp = fid & 31;                // fid%8 == grp%8 -> same-grp same XCD
  const int b = grp >> 4, h = grp & 15;

  const int tid = threadIdx.x, w = tid >> 6, lane = tid & 63;
  const int ln = lane & 15, quad = lane >> 4;
  const int qh = w & 1, kh = w >> 1;       // quadrant ownership

  const bf16* qbase  = qkv + (size_t)h * 262144 + (size_t)b * 131072;
  const bf16* kbase  = qbase + 4194304;
  const bf16* vtbase = qbase + 8388608;    // [d][t], d-stride 2048

  // ---- staging lane constants (wave w stages LDS rows w*16..w*16+15) ----
  const int l8 = lane & 7, r8 = lane >> 3;
  const int slot = l8 ^ r8;                // swizzle: LDS[row][s] = G[row][s^(row&7)]
  const int p0 = w * 16 + r8, p1 = p0 + 8;
  // kperm(p): LDS row p holds K row (p&32) | ((p&12)<<1) | ((p&16)>>2) | (p&3)
  const int kp0 = (p0 & 32) | ((p0 & 12) << 1) | ((p0 & 16) >> 2) | (p0 & 3);
  const int kp1 = (p1 & 32) | ((p1 & 12) << 1) | ((p1 & 16) >> 2) | (p1 & 3);
  const bf16* gkp0 = kbase + kp0 * 64 + slot * 8;   // advanced by +4096/tile
  const bf16* gkp1 = kbase + kp1 * 64 + slot * 8;
  const bf16* gvp0 = vtbase + p0 * 2048 + slot * 8; // advanced by +64/tile
  const bf16* gvp1 = gvp0 + 8 * 2048;

  // ---- fragment-read lane constants (element offsets into [64][64]) ----
  const int sw = ln & 7;
  const int cc0 = ((quad    ) ^ sw) * 8;   // granule for d/kv half 0
  const int cc1 = ((quad + 4) ^ sw) * 8;   // granule for d/kv half 1
  const int cck = kh ? cc1 : cc0;          // V col granule for this kv-half
  const int krow0 = (kh * 32 + ln) * 64;   // K row offset, nfl=0 (elems)
  const int ka0 = krow0 + cc0, ka1 = krow0 + cc1;   // loop-invariant bases
  const int voff = ln * 64 + cck;

  v8bf vone;
  {
    unsigned short u = 0x3F80;             // 1.0 bf16
    __bf16 e = *reinterpret_cast<__bf16*>(&u);
    #pragma unroll
    for (int jj = 0; jj < 8; ++jj) vone[jj] = e;
  }
  const v4f vzero = {0.f, 0.f, 0.f, 0.f};
  const float NEG = -30000.0f;

  #define STAGE2(BUF) {                                          \
    load16_lds(gkp0, &sh.t.K[BUF][w * 16][0]);                   \
    load16_lds(gkp1, &sh.t.K[BUF][w * 16 + 8][0]);               \
    load16_lds(gvp0, &sh.t.V[BUF][w * 16][0]);                   \
    load16_lds(gvp1, &sh.t.V[BUF][w * 16 + 8][0]);               \
    gkp0 += 4096; gkp1 += 4096; gvp0 += 64; gvp1 += 64; }

  const int row0 = mt * 64;
  const int qrow = row0 + qh * 32;         // wave's q rows: qrow..qrow+31

  // Q fragments (B-operand): Q[qrow+mc*16+ln][ks*32 + quad*8 + j]
  v8bf aq[2][2];
  #pragma unroll
  for (int mc = 0; mc < 2; ++mc)
    #pragma unroll
    for (int ks = 0; ks < 2; ++ks)
      aq[mc][ks] = *(const v8bf*)(qbase +
          (size_t)(qrow + mc * 16 + ln) * 64 + ks * 32 + quad * 8);

  v4f o[2][4], lacc[2];
  #pragma unroll
  for (int mc = 0; mc < 2; ++mc) {
    lacc[mc] = vzero;
    #pragma unroll
    for (int dt = 0; dt < 4; ++dt) o[mc][dt] = vzero;
  }

  const int kb_end = mt;
  int kb = 0;
  STAGE2(0)                                // stage kb=0; ptrs now at kb=1

  // TILE(BUF): BUF is a compile-time literal -> ds_read addrs fold to
  // base VGPR + offset:imm; zero per-tile address VALU.
  #define TILE(BUF)                                                        \
  {                                                                        \
    __syncthreads();                       /* publishes BUF */             \
    const bf16* krB = &sh.t.K[BUF][0][0];                                  \
    const bf16* vrB = &sh.t.V[BUF][0][0];                                  \
    v8bf kf[2][2], vf[4];                                                  \
    kf[0][0] = *(const v8bf*)(krB + ka0);                                  \
    kf[1][0] = *(const v8bf*)(krB + ka1);                                  \
    kf[0][1] = *(const v8bf*)(krB + ka0 + 1024);                           \
    kf[1][1] = *(const v8bf*)(krB + ka1 + 1024);                           \
    vf[0] = *(const v8bf*)(vrB + voff);                                    \
    vf[1] = *(const v8bf*)(vrB + voff + 1024);                             \
    vf[2] = *(const v8bf*)(vrB + voff + 2048);                             \
    vf[3] = *(const v8bf*)(vrB + voff + 3072);                             \
    if (kb < kb_end) STAGE2(BUF ^ 1)                                       \
    _Pragma("unroll")                                                      \
    for (int mc = 0; mc < 2; ++mc) {                                       \
      __builtin_amdgcn_s_setprio(1);                                       \
      v4f s[2];                                                            \
      s[0] = vzero; s[1] = vzero;                                          \
      _Pragma("unroll")                                                    \
      for (int ks = 0; ks < 2; ++ks) {                                     \
        s[0] = MFMA16(kf[ks][0], aq[mc][ks], s[0]);                        \
        s[1] = MFMA16(kf[ks][1], aq[mc][ks], s[1]);                        \
      }                                                                    \
      __builtin_amdgcn_s_setprio(0);                                       \
      const int qg = qrow + mc * 16 + ln;                                  \
      if (kb == kb_end) {                  /* causal mask (diagonal) */    \
        _Pragma("unroll")                                                  \
        for (int nfl = 0; nfl < 2; ++nfl) {                                \
          const int kc = kb * 64 + kh * 32 + quad * 8 + nfl * 4;           \
          _Pragma("unroll")                                                \
          for (int r = 0; r < 4; ++r)                                      \
            if (kc + r > qg) s[nfl][r] = NEG;                              \
        }                                                                  \
      }                                                                    \
      float ex[2][4];                                                      \
      _Pragma("unroll")                                                    \
      for (int nfl = 0; nfl < 2; ++nfl)                                    \
        _Pragma("unroll")                                                  \
        for (int r = 0; r < 4; ++r)                                        \
          ex[nfl][r] = exp2f(s[nfl][r]);                                   \
      union { u32 uw[4]; v8bf v; } pu;                                     \
      _Pragma("unroll")                                                    \
      for (int nfl = 0; nfl < 2; ++nfl)                                    \
        _Pragma("unroll")                                                  \
        for (int wi = 0; wi < 2; ++wi)                                     \
          asm("v_cvt_pk_bf16_f32 %0, %1, %2"                               \
              : "=v"(pu.uw[nfl * 2 + wi])                                  \
              : "v"(ex[nfl][2 * wi]), "v"(ex[nfl][2 * wi + 1]));           \
      __builtin_amdgcn_s_setprio(1);                                       \
      lacc[mc] = MFMA16(pu.v, vone, lacc[mc]);                             \
      _Pragma("unroll")                                                    \
      for (int dt = 0; dt < 4; ++dt)                                       \
        o[mc][dt] = MFMA16(pu.v, vf[dt], o[mc][dt]);                       \
      __builtin_amdgcn_s_setprio(0);                                       \
    }                                                                      \
  }

  while (true) {
    TILE(0)
    if (kb >= kb_end) break;
    ++kb;
    TILE(1)
    if (kb >= kb_end) break;
    ++kb;
  }
  #undef TILE
  #undef STAGE2

  // ---- combine kv-half partials (kh=1 -> LDS, kh=0 adds) & epilogue ----
  __syncthreads();                         // all tile reads done; t is dead
  if (kh == 1) {
    #pragma unroll
    for (int mc = 0; mc < 2; ++mc) {
      #pragma unroll
      for (int dt = 0; dt < 4; ++dt)
        *(v4f*)&sh.c.O[qh][dt * 16 + ln][mc * 16 + quad * 4] = o[mc][dt];
      if (ln == 0)
        *(v4f*)&sh.c.L[qh][mc * 16 + quad * 4] = lacc[mc];
    }
  }
  __syncthreads();
  if (kh == 0) {
    #pragma unroll
    for (int mc = 0; mc < 2; ++mc) {
      v4f pl = *(const v4f*)&sh.c.L[qh][mc * 16 + quad * 4];
      v4f inv;
      #pragma unroll
      for (int r = 0; r < 4; ++r) inv[r] = 1.0f / (lacc[mc][r] + pl[r]);
      #pragma unroll
      for (int dt = 0; dt < 4; ++dt) {
        v4f po = *(const v4f*)&sh.c.O[qh][dt * 16 + ln][mc * 16 + quad * 4];
        #pragma unroll
        for (int r = 0; r < 4; ++r) {
          int m = b * 2048 + qrow + mc * 16 + quad * 4 + r;
          att[(size_t)m * 1024 + h * 64 + dt * 16 + ln] =
              f2b((o[mc][dt][r] + po[r]) * inv[r]);
        }
      }
    }
  }
}

// ---------------------------------------------------------------------------
// Kernel 3: output projection + bias, fp32 out. 128x64 tiles, BK=32,
// double-buffered, ONE barrier per k-step, kt unrolled x2 (literal buf),
// staging via pointer induction, slot-swizzled LDS. grid (32, 16).
// ---------------------------------------------------------------------------
__global__ __launch_bounds__(256) void out_gemm_kernel(
    const bf16* __restrict__ att, const bf16* __restrict__ wot,
    const float* __restrict__ bo, float* __restrict__ out)
{
  __shared__ __align__(16) bf16 Ash[2][128][32];
  __shared__ __align__(16) bf16 Bsh[2][64][32];

  const int mt = blockIdx.x, nt = blockIdx.y;
  const int tid = threadIdx.x, w = tid >> 6, lane = tid & 63;
  const int ln = lane & 15, quad = lane >> 4;
  const int wm = w >> 1, wn = w & 1;
  const int m0 = mt * 128, n0 = nt * 64;

  const v4f vzero = {0.f, 0.f, 0.f, 0.f};
  v4f acc[4][2];
  #pragma unroll
  for (int mf = 0; mf < 4; ++mf)
    #pragma unroll
    for (int nf = 0; nf < 2; ++nf) acc[mf][nf] = vzero;

  // staging: linear LDS dest; global source segment pre-swizzled (see K1).
  const int srow = lane >> 2;
  const int sseg = ((lane & 3) ^ ((lane >> 3) & 3)) * 8;
  const bf16* ga = att + (size_t)(m0 + 32 * w + srow) * 1024 + sseg;
  const bf16* gb = wot + (size_t)(n0 + 16 * w + srow) * 1024 + sseg;

  const int fseg = (quad ^ ((ln >> 1) & 3)) * 8;

  load16_lds(ga,             &Ash[0][32 * w][0]);
  load16_lds(ga + 16 * 1024, &Ash[0][32 * w + 16][0]);
  load16_lds(gb,             &Bsh[0][16 * w][0]);
  ga += 32; gb += 32;

  int kt = 0;
  #define OTILE(BUF)                                                     \
  {                                                                      \
    __syncthreads();                                                     \
    v8bf af[4], bfv[2];                                                  \
    _Pragma("unroll")                                                    \
    for (int mf = 0; mf < 4; ++mf)                                       \
      af[mf] = *(const v8bf*)&Ash[BUF][wm * 64 + mf * 16 + ln][fseg];    \
    _Pragma("unroll")                                                    \
    for (int nf = 0; nf < 2; ++nf)                                       \
      bfv[nf] = *(const v8bf*)&Bsh[BUF][wn * 32 + nf * 16 + ln][fseg];   \
    if (kt < 31) {                                                       \
      load16_lds(ga,             &Ash[BUF ^ 1][32 * w][0]);              \
      load16_lds(ga + 16 * 1024, &Ash[BUF ^ 1][32 * w + 16][0]);         \
      load16_lds(gb,             &Bsh[BUF ^ 1][16 * w][0]);              \
      ga += 32; gb += 32;                                                \
    }                                                                    \
    _Pragma("unroll")                                                    \
    for (int mf = 0; mf < 4; ++mf)                                       \
      _Pragma("unroll")                                                  \
      for (int nf = 0; nf < 2; ++nf)                                     \
        acc[mf][nf] = MFMA16(af[mf], bfv[nf], acc[mf][nf]);              \
    ++kt;                                                                \
  }

  #pragma unroll 1
  for (int it = 0; it < 16; ++it) {
    OTILE(0)
    OTILE(1)
  }
  #undef OTILE

  #pragma unroll
  for (int nf = 0; nf < 2; ++nf) {
    int j = n0 + wn * 32 + nf * 16 + ln;
    float bias = bo[j];
    #pragma unroll
    for (int mf = 0; mf < 4; ++mf)
      #pragma unroll
      for (int r = 0; r < 4; ++r) {
        int m = m0 + wm * 64 + mf * 16 + quad * 4 + r;
        out[(size_t)m * 1024 + j] = acc[mf][nf][r] + bias;
      }
  }
}

extern "C" void kernel_launch(void* const* d_in, const int* in_sizes, int n_in,
                              void* d_out, int out_size, void* d_ws, size_t ws_size,
                              hipStream_t stream) {
  const float* x  = (const float*)d_in[0];
  const float* Wq = (const float*)d_in[1];
  const float* Wk = (const float*)d_in[2];
  const float* Wv = (const float*)d_in[3];
  const float* Wo = (const float*)d_in[4];
  const float* bo = (const float*)d_in[5];
  float* out = (float*)d_out;

  bf16* xb  = (bf16*)d_ws;
  bf16* wt  = xb + 4194304;
  bf16* wot = xb + 7340032;
  bf16* qkv = xb + 8388608;
  bf16* att = xb + 20971520;

  prep_kernel<<<6144, 256, 0, stream>>>(x, Wq, Wk, Wv, Wo, xb, wt, wot);
  qkv_gemm_kernel<<<dim3(16, 16), 512, 0, stream>>>(xb, wt, qkv);
  attn_kernel<<<1024, 256, 0, stream>>>(qkv, att);
  out_gemm_kernel<<<dim3(32, 16), 256, 0, stream>>>(att, wot, bo, out);
}